// Round 1
// baseline (766.609 us; speedup 1.0000x reference)
//
#include <hip/hip_runtime.h>
#include <math.h>

#define N_NODES 50000
#define N_EDGES 800000
#define E_TOT   (N_EDGES + N_NODES)   // 850000 edges incl. self loops

// ---------- ordered-uint mapping for float atomic max ----------
__device__ __forceinline__ unsigned flip_f(float f) {
    unsigned u = __float_as_uint(f);
    return (u & 0x80000000u) ? ~u : (u | 0x80000000u);
}
__device__ __forceinline__ float unflip_f(unsigned m) {
    unsigned u = (m & 0x80000000u) ? (m & 0x7FFFFFFFu) : ~m;
    return __uint_as_float(u);
}

// ---------- layer 1 GEMM: h1 = x @ W1  [N,128]x[128,128], fused scores ----------
__global__ __launch_bounds__(128) void gemm1_kernel(
    const float* __restrict__ x, const float* __restrict__ W,
    const float* __restrict__ a_src, const float* __restrict__ a_dst,
    float* __restrict__ h, float* __restrict__ s_src, float* __restrict__ s_dst)
{
    __shared__ float xs[128];
    const int row = blockIdx.x;
    const int tid = threadIdx.x;          // channel 0..127 (head = tid>>6)
    xs[tid] = x[row * 128 + tid];
    __syncthreads();
    float acc = 0.f;
    #pragma unroll 16
    for (int k = 0; k < 128; ++k) acc += xs[k] * W[k * 128 + tid];
    h[row * 128 + tid] = acc;
    float vs = acc * a_src[tid];
    float vd = acc * a_dst[tid];
    #pragma unroll
    for (int off = 32; off >= 1; off >>= 1) {
        vs += __shfl_xor(vs, off, 64);
        vd += __shfl_xor(vd, off, 64);
    }
    if ((tid & 63) == 0) {
        int head = tid >> 6;
        s_src[row * 2 + head] = vs;
        s_dst[row * 2 + head] = vd;
    }
}

// ---------- layer 2 GEMM: g = h2 @ W2  [N,128]x[128,32], fused scores ----------
__global__ __launch_bounds__(256) void gemm2_kernel(
    const float* __restrict__ h, const float* __restrict__ W,
    const float* __restrict__ a_src, const float* __restrict__ a_dst,
    float* __restrict__ g, float* __restrict__ s_src, float* __restrict__ s_dst)
{
    __shared__ float xs[8][128];
    const int col = threadIdx.x;          // 0..31
    const int r   = threadIdx.y;          // 0..7
    const int row = blockIdx.x * 8 + r;
    if (row < N_NODES) {
        #pragma unroll
        for (int i = 0; i < 4; ++i) xs[r][col + i * 32] = h[row * 128 + col + i * 32];
    }
    __syncthreads();
    if (row >= N_NODES) return;
    float acc = 0.f;
    #pragma unroll 16
    for (int k = 0; k < 128; ++k) acc += xs[r][k] * W[k * 32 + col];
    g[row * 32 + col] = acc;
    float vs = acc * a_src[col];
    float vd = acc * a_dst[col];
    #pragma unroll
    for (int off = 16; off >= 1; off >>= 1) {
        vs += __shfl_xor(vs, off, 32);
        vd += __shfl_xor(vd, off, 32);
    }
    if (col == 0) { s_src[row] = vs; s_dst[row] = vd; }
}

// ---------- per-edge leaky-relu score + segment max ----------
template<int H>
__global__ void edge_max_kernel(
    const int* __restrict__ esrc, const int* __restrict__ edst,
    const float* __restrict__ s_src, const float* __restrict__ s_dst,
    float* __restrict__ ebuf, unsigned* __restrict__ emax)
{
    int idx = blockIdx.x * blockDim.x + threadIdx.x;
    int e = idx / H, hh = idx % H;
    if (e >= E_TOT) return;
    int s, d;
    if (e < N_EDGES) { s = esrc[e]; d = edst[e]; } else { s = d = e - N_EDGES; }
    float v = s_src[s * H + hh] + s_dst[d * H + hh];
    v = v > 0.f ? v : 0.2f * v;
    ebuf[e * H + hh] = v;
    atomicMax(&emax[d * H + hh], flip_f(v));
}

// ---------- per-edge exp + segment sum ----------
template<int H>
__global__ void edge_exp_kernel(
    const int* __restrict__ esrc, const int* __restrict__ edst,
    float* __restrict__ ebuf, const unsigned* __restrict__ emax,
    float* __restrict__ den)
{
    int idx = blockIdx.x * blockDim.x + threadIdx.x;
    int e = idx / H, hh = idx % H;
    if (e >= E_TOT) return;
    int d;
    if (e < N_EDGES) { d = edst[e]; } else { d = e - N_EDGES; }
    float m = unflip_f(emax[d * H + hh]);
    float ee = expf(ebuf[e * H + hh] - m);
    ebuf[e * H + hh] = ee;
    atomicAdd(&den[d * H + hh], ee);
}

// ---------- layer 1 aggregation: one wave per edge, 128 channels ----------
__global__ __launch_bounds__(256) void edge_agg1_kernel(
    const int* __restrict__ esrc, const int* __restrict__ edst,
    const float* __restrict__ ebuf, const float* __restrict__ den,
    const float* __restrict__ h, float* __restrict__ agg)
{
    const int wid  = threadIdx.x >> 6;
    const int lane = threadIdx.x & 63;
    const int e = blockIdx.x * 4 + wid;
    if (e >= E_TOT) return;
    int s, d;
    if (e < N_EDGES) { s = esrc[e]; d = edst[e]; } else { s = d = e - N_EDGES; }
    const float a0 = ebuf[e * 2]     / den[d * 2];
    const float a1 = ebuf[e * 2 + 1] / den[d * 2 + 1];
    const float v0 = h[s * 128 + lane];
    const float v1 = h[s * 128 + 64 + lane];
    atomicAdd(&agg[d * 128 + lane],      v0 * a0);
    atomicAdd(&agg[d * 128 + 64 + lane], v1 * a1);
}

// ---------- layer 2 aggregation: 32 threads per edge ----------
__global__ void edge_agg2_kernel(
    const int* __restrict__ esrc, const int* __restrict__ edst,
    const float* __restrict__ ebuf, const float* __restrict__ den,
    const float* __restrict__ g, float* __restrict__ agg)
{
    int idx = blockIdx.x * blockDim.x + threadIdx.x;
    int e = idx >> 5, c = idx & 31;
    if (e >= E_TOT) return;
    int s, d;
    if (e < N_EDGES) { s = esrc[e]; d = edst[e]; } else { s = d = e - N_EDGES; }
    float a = ebuf[e] / den[d];
    atomicAdd(&agg[d * 32 + c], g[s * 32 + c] * a);
}

// ---------- node epilogues ----------
__global__ void bias_elu_kernel(float* __restrict__ agg, const float* __restrict__ b)
{
    int idx = blockIdx.x * blockDim.x + threadIdx.x;
    if (idx >= N_NODES * 128) return;
    float v = agg[idx] + b[idx & 127];
    agg[idx] = v > 0.f ? v : expm1f(v);
}

__global__ void bias_out_kernel(const float* __restrict__ agg, const float* __restrict__ b,
                                float* __restrict__ out)
{
    int idx = blockIdx.x * blockDim.x + threadIdx.x;
    if (idx >= N_NODES * 32) return;
    out[idx] = agg[idx] + b[idx & 31];
}

extern "C" void kernel_launch(void* const* d_in, const int* in_sizes, int n_in,
                              void* d_out, int out_size, void* d_ws, size_t ws_size,
                              hipStream_t stream)
{
    const float* x   = (const float*)d_in[0];
    const int*   ei  = (const int*)d_in[1];     // [2, E] int32: row0 = src, row1 = dst
    const float* W1  = (const float*)d_in[2];
    const float* a1s = (const float*)d_in[3];
    const float* a1d = (const float*)d_in[4];
    const float* b1  = (const float*)d_in[5];
    const float* W2  = (const float*)d_in[6];
    const float* a2s = (const float*)d_in[7];
    const float* a2d = (const float*)d_in[8];
    const float* b2  = (const float*)d_in[9];
    float* out = (float*)d_out;

    const int* esrc = ei;
    const int* edst = ei + N_EDGES;

    // -------- workspace layout (floats) --------
    float* ws = (float*)d_ws;
    float*    h1    = ws;                                   // N*128
    float*    agg1  = h1   + (size_t)N_NODES * 128;         // N*128 (becomes h2 after elu)
    float*    s1s   = agg1 + (size_t)N_NODES * 128;         // 2N
    float*    s1d   = s1s  + 2 * N_NODES;                   // 2N
    unsigned* emax1 = (unsigned*)(s1d + 2 * N_NODES);       // 2N
    float*    den1  = (float*)(emax1 + 2 * N_NODES);        // 2N
    float*    e1    = den1 + 2 * N_NODES;                   // E_TOT*2
    // layer 2 reuses the h1 region (dead after layer-1 aggregation)
    float*    g2    = h1;                                   // N*32
    float*    agg2  = g2   + (size_t)N_NODES * 32;          // N*32
    float*    s2s   = agg2 + (size_t)N_NODES * 32;          // N
    float*    s2d   = s2s  + N_NODES;                       // N
    unsigned* emax2 = (unsigned*)(s2d + N_NODES);           // N
    float*    den2  = (float*)(emax2 + N_NODES);            // N
    float*    e2    = den2 + N_NODES;                       // E_TOT

    // -------- layer 1 --------
    hipMemsetAsync(agg1,  0, (size_t)N_NODES * 128 * 4, stream);
    hipMemsetAsync(emax1, 0, (size_t)N_NODES * 2 * 4,   stream);
    hipMemsetAsync(den1,  0, (size_t)N_NODES * 2 * 4,   stream);

    gemm1_kernel<<<N_NODES, 128, 0, stream>>>(x, W1, a1s, a1d, h1, s1s, s1d);

    int nthr = E_TOT * 2;
    edge_max_kernel<2><<<(nthr + 255) / 256, 256, 0, stream>>>(esrc, edst, s1s, s1d, e1, emax1);
    edge_exp_kernel<2><<<(nthr + 255) / 256, 256, 0, stream>>>(esrc, edst, e1, emax1, den1);
    edge_agg1_kernel<<<(E_TOT + 3) / 4, 256, 0, stream>>>(esrc, edst, e1, den1, h1, agg1);
    bias_elu_kernel<<<(N_NODES * 128 + 255) / 256, 256, 0, stream>>>(agg1, b1);

    // -------- layer 2 (agg1 now holds h2) --------
    hipMemsetAsync(agg2,  0, (size_t)N_NODES * 32 * 4, stream);
    hipMemsetAsync(emax2, 0, (size_t)N_NODES * 4,      stream);
    hipMemsetAsync(den2,  0, (size_t)N_NODES * 4,      stream);

    gemm2_kernel<<<(N_NODES + 7) / 8, dim3(32, 8), 0, stream>>>(agg1, W2, a2s, a2d, g2, s2s, s2d);

    nthr = E_TOT;
    edge_max_kernel<1><<<(nthr + 255) / 256, 256, 0, stream>>>(esrc, edst, s2s, s2d, e2, emax2);
    edge_exp_kernel<1><<<(nthr + 255) / 256, 256, 0, stream>>>(esrc, edst, e2, emax2, den2);
    edge_agg2_kernel<<<(E_TOT * 32 + 255) / 256, 256, 0, stream>>>(esrc, edst, e2, den2, g2, agg2);
    bias_out_kernel<<<(N_NODES * 32 + 255) / 256, 256, 0, stream>>>(agg2, b2, out);
}

// Round 2
// 472.698 us; speedup vs baseline: 1.6218x; 1.6218x over previous
//
#include <hip/hip_runtime.h>
#include <math.h>

#define N_NODES 50000
#define N_EDGES 800000
#define E_TOT   (N_EDGES + N_NODES)   // 850000 edges incl. self loops

// ---------- layer 1 GEMM: h1 = x @ W1  [N,128]x[128,128], fused scores ----------
__global__ __launch_bounds__(128) void gemm1_kernel(
    const float* __restrict__ x, const float* __restrict__ W,
    const float* __restrict__ a_src, const float* __restrict__ a_dst,
    float* __restrict__ h, float* __restrict__ s_src, float* __restrict__ s_dst)
{
    __shared__ float xs[128];
    const int row = blockIdx.x;
    const int tid = threadIdx.x;          // channel 0..127 (head = tid>>6)
    xs[tid] = x[row * 128 + tid];
    __syncthreads();
    float acc = 0.f;
    #pragma unroll 16
    for (int k = 0; k < 128; ++k) acc += xs[k] * W[k * 128 + tid];
    h[row * 128 + tid] = acc;
    float vs = acc * a_src[tid];
    float vd = acc * a_dst[tid];
    #pragma unroll
    for (int off = 32; off >= 1; off >>= 1) {
        vs += __shfl_xor(vs, off, 64);
        vd += __shfl_xor(vd, off, 64);
    }
    if ((tid & 63) == 0) {
        int head = tid >> 6;
        s_src[row * 2 + head] = vs;
        s_dst[row * 2 + head] = vd;
    }
}

// ---------- layer 2 GEMM: g = h2 @ W2  [N,128]x[128,32], fused scores ----------
__global__ __launch_bounds__(256) void gemm2_kernel(
    const float* __restrict__ h, const float* __restrict__ W,
    const float* __restrict__ a_src, const float* __restrict__ a_dst,
    float* __restrict__ g, float* __restrict__ s_src, float* __restrict__ s_dst)
{
    __shared__ float xs[8][128];
    const int col = threadIdx.x;          // 0..31
    const int r   = threadIdx.y;          // 0..7
    const int row = blockIdx.x * 8 + r;
    if (row < N_NODES) {
        #pragma unroll
        for (int i = 0; i < 4; ++i) xs[r][col + i * 32] = h[row * 128 + col + i * 32];
    }
    __syncthreads();
    if (row >= N_NODES) return;
    float acc = 0.f;
    #pragma unroll 16
    for (int k = 0; k < 128; ++k) acc += xs[r][k] * W[k * 32 + col];
    g[row * 32 + col] = acc;
    float vs = acc * a_src[col];
    float vd = acc * a_dst[col];
    #pragma unroll
    for (int off = 16; off >= 1; off >>= 1) {
        vs += __shfl_xor(vs, off, 32);
        vd += __shfl_xor(vd, off, 32);
    }
    if (col == 0) { s_src[row] = vs; s_dst[row] = vd; }
}

// ---------- CSR build: histogram ----------
__global__ void hist_kernel(const int* __restrict__ edst, int* __restrict__ deg)
{
    int e = blockIdx.x * blockDim.x + threadIdx.x;
    if (e >= E_TOT) return;
    int d = (e < N_EDGES) ? edst[e] : (e - N_EDGES);
    atomicAdd(&deg[d], 1);
}

// ---------- CSR build: single-block exclusive scan (N=50000) ----------
__global__ __launch_bounds__(1024) void scan_kernel(
    const int* __restrict__ deg, int* __restrict__ offsets, int* __restrict__ cursor)
{
    __shared__ int buf[1024];
    __shared__ int s_carry;
    const int t = threadIdx.x;
    if (t == 0) s_carry = 0;
    __syncthreads();
    for (int base = 0; base < N_NODES; base += 1024) {
        int i = base + t;
        int v = (i < N_NODES) ? deg[i] : 0;
        buf[t] = v;
        __syncthreads();
        // Hillis-Steele inclusive scan
        #pragma unroll
        for (int off = 1; off < 1024; off <<= 1) {
            int x = (t >= off) ? buf[t - off] : 0;
            __syncthreads();
            buf[t] += x;
            __syncthreads();
        }
        int carry = s_carry;
        if (i < N_NODES) {
            int excl = carry + buf[t] - v;
            offsets[i] = excl;
            cursor[i]  = excl;
        }
        __syncthreads();
        if (t == 0) s_carry = carry + buf[1023];
        __syncthreads();
    }
    if (t == 0) offsets[N_NODES] = s_carry;   // == E_TOT
}

// ---------- CSR build: scatter src ids by destination ----------
__global__ void scatter_kernel(const int* __restrict__ esrc, const int* __restrict__ edst,
                               int* __restrict__ cursor, int* __restrict__ csr_src)
{
    int e = blockIdx.x * blockDim.x + threadIdx.x;
    if (e >= E_TOT) return;
    int s, d;
    if (e < N_EDGES) { s = esrc[e]; d = edst[e]; } else { s = d = e - N_EDGES; }
    int pos = atomicAdd(&cursor[d], 1);
    csr_src[pos] = s;
}

// ---------- layer 1 fused: online softmax + aggregate + bias + ELU ----------
// one wave (64 lanes) per destination node; lane owns ch {lane, lane+64}
__global__ __launch_bounds__(256) void fused_agg1_kernel(
    const int* __restrict__ csr_src, const int* __restrict__ offsets,
    const float* __restrict__ s_src, const float* __restrict__ s_dst,
    const float* __restrict__ h, const float* __restrict__ b,
    float* __restrict__ h2)
{
    const int wid  = threadIdx.x >> 6;
    const int lane = threadIdx.x & 63;
    const int d = blockIdx.x * 4 + wid;
    if (d >= N_NODES) return;
    const int beg = offsets[d], end = offsets[d + 1];
    const float sd0 = s_dst[d * 2], sd1 = s_dst[d * 2 + 1];
    float m0 = -INFINITY, m1 = -INFINITY;
    float den0 = 0.f, den1 = 0.f, acc0 = 0.f, acc1 = 0.f;
    for (int i = beg; i < end; ++i) {
        const int s = csr_src[i];
        float v0 = s_src[s * 2]     + sd0;  v0 = v0 > 0.f ? v0 : 0.2f * v0;
        float v1 = s_src[s * 2 + 1] + sd1;  v1 = v1 > 0.f ? v1 : 0.2f * v1;
        const float nm0 = fmaxf(m0, v0), nm1 = fmaxf(m1, v1);
        const float sc0 = __expf(m0 - nm0), sc1 = __expf(m1 - nm1);
        const float e0  = __expf(v0 - nm0), e1  = __expf(v1 - nm1);
        const float hv0 = h[s * 128 + lane];
        const float hv1 = h[s * 128 + 64 + lane];
        den0 = den0 * sc0 + e0;
        den1 = den1 * sc1 + e1;
        acc0 = acc0 * sc0 + e0 * hv0;
        acc1 = acc1 * sc1 + e1 * hv1;
        m0 = nm0; m1 = nm1;
    }
    float o0 = acc0 / den0 + b[lane];
    float o1 = acc1 / den1 + b[64 + lane];
    o0 = o0 > 0.f ? o0 : expm1f(o0);
    o1 = o1 > 0.f ? o1 : expm1f(o1);
    h2[d * 128 + lane]      = o0;
    h2[d * 128 + 64 + lane] = o1;
}

// ---------- layer 2 fused: online softmax + aggregate + bias -> out ----------
// one 32-lane group per destination node
__global__ __launch_bounds__(256) void fused_agg2_kernel(
    const int* __restrict__ csr_src, const int* __restrict__ offsets,
    const float* __restrict__ s_src, const float* __restrict__ s_dst,
    const float* __restrict__ g, const float* __restrict__ b,
    float* __restrict__ out)
{
    const int grp  = threadIdx.x >> 5;
    const int lane = threadIdx.x & 31;
    const int d = blockIdx.x * 8 + grp;
    if (d >= N_NODES) return;
    const int beg = offsets[d], end = offsets[d + 1];
    const float sd = s_dst[d];
    float m = -INFINITY, den = 0.f, acc = 0.f;
    for (int i = beg; i < end; ++i) {
        const int s = csr_src[i];
        float v = s_src[s] + sd;  v = v > 0.f ? v : 0.2f * v;
        const float nm = fmaxf(m, v);
        const float sc = __expf(m - nm);
        const float e  = __expf(v - nm);
        const float gv = g[s * 32 + lane];
        den = den * sc + e;
        acc = acc * sc + e * gv;
        m = nm;
    }
    out[d * 32 + lane] = acc / den + b[lane];
}

extern "C" void kernel_launch(void* const* d_in, const int* in_sizes, int n_in,
                              void* d_out, int out_size, void* d_ws, size_t ws_size,
                              hipStream_t stream)
{
    const float* x   = (const float*)d_in[0];
    const int*   ei  = (const int*)d_in[1];     // [2, E] int32: row0 = src, row1 = dst
    const float* W1  = (const float*)d_in[2];
    const float* a1s = (const float*)d_in[3];
    const float* a1d = (const float*)d_in[4];
    const float* b1  = (const float*)d_in[5];
    const float* W2  = (const float*)d_in[6];
    const float* a2s = (const float*)d_in[7];
    const float* a2d = (const float*)d_in[8];
    const float* b2  = (const float*)d_in[9];
    float* out = (float*)d_out;

    const int* esrc = ei;
    const int* edst = ei + N_EDGES;

    // -------- workspace layout --------
    float* ws = (float*)d_ws;
    float* h1  = ws;                                 // N*128
    float* h2  = h1  + (size_t)N_NODES * 128;        // N*128
    float* s1s = h2  + (size_t)N_NODES * 128;        // 2N
    float* s1d = s1s + 2 * N_NODES;                  // 2N
    float* s2s = s1d + 2 * N_NODES;                  // N
    float* s2d = s2s + N_NODES;                      // N
    int* deg     = (int*)(s2d + N_NODES);            // N
    int* offsets = deg + N_NODES;                    // N+1
    int* cursor  = offsets + N_NODES + 1;            // N
    int* csr_src = cursor + N_NODES;                 // E_TOT
    // g2 reuses h1's region (h1 dead after fused_agg1)
    float* g2 = h1;                                  // N*32

    // -------- CSR build (graph is shared by both layers) --------
    hipMemsetAsync(deg, 0, (size_t)N_NODES * 4, stream);
    hist_kernel<<<(E_TOT + 255) / 256, 256, 0, stream>>>(edst, deg);
    scan_kernel<<<1, 1024, 0, stream>>>(deg, offsets, cursor);
    scatter_kernel<<<(E_TOT + 255) / 256, 256, 0, stream>>>(esrc, edst, cursor, csr_src);

    // -------- layer 1 --------
    gemm1_kernel<<<N_NODES, 128, 0, stream>>>(x, W1, a1s, a1d, h1, s1s, s1d);
    fused_agg1_kernel<<<(N_NODES + 3) / 4, 256, 0, stream>>>(
        csr_src, offsets, s1s, s1d, h1, b1, h2);

    // -------- layer 2 --------
    gemm2_kernel<<<(N_NODES + 7) / 8, dim3(32, 8), 0, stream>>>(h2, W2, a2s, a2d, g2, s2s, s2d);
    fused_agg2_kernel<<<(N_NODES + 7) / 8, 256, 0, stream>>>(
        csr_src, offsets, s2s, s2d, g2, b2, out);
}

// Round 3
// 412.642 us; speedup vs baseline: 1.8578x; 1.1455x over previous
//
#include <hip/hip_runtime.h>
#include <math.h>

#define N_NODES 50000
#define N_EDGES 800000
#define E_TOT   (N_EDGES + N_NODES)   // 850000 edges incl. self loops

// ================= layer 1 GEMM: h1 = x @ W1  [N,128]x[128,128] ================
// grid = ceil(N/64)*2 ; block 128 = (16 colT, 8 rowT)
// block handles 64 rows x 64 cols (col-half == head); K staged in 2 chunks of 64
// thread: 4 cols (c = colT + 16j), 8 rows (r = rowT + 8i), 32 accumulators
__global__ __launch_bounds__(128) void gemm1_tiled(
    const float* __restrict__ x, const float* __restrict__ W,
    const float* __restrict__ a_src, const float* __restrict__ a_dst,
    float* __restrict__ h, float* __restrict__ s_src, float* __restrict__ s_dst)
{
    __shared__ float xs[64][68];
    __shared__ float wt[64][68];
    const int tid  = threadIdx.x;
    const int colT = tid & 15;
    const int rowT = tid >> 4;
    const int half = blockIdx.x & 1;          // head
    const int r0   = (blockIdx.x >> 1) * 64;
    const int c0   = half * 64;

    float acc[4][8];
    #pragma unroll
    for (int j = 0; j < 4; ++j)
        #pragma unroll
        for (int i = 0; i < 8; ++i) acc[j][i] = 0.f;

    for (int kc = 0; kc < 2; ++kc) {
        const int kbase = kc * 64;
        // stage xs: 64 rows x 16 quads
        #pragma unroll
        for (int it = 0; it < 8; ++it) {
            int q = it * 128 + tid;
            int row = q >> 4, k4 = q & 15;
            float4 v = make_float4(0.f, 0.f, 0.f, 0.f);
            if (r0 + row < N_NODES)
                v = *(const float4*)&x[(size_t)(r0 + row) * 128 + kbase + k4 * 4];
            *(float4*)&xs[row][k4 * 4] = v;
        }
        // stage wt[c][k] = W[kbase+k][c0+c]: 64 c x 16 quads (gather 4 k's per quad)
        #pragma unroll
        for (int it = 0; it < 8; ++it) {
            int q = it * 128 + tid;
            int c = q & 63, k4 = q >> 6;
            float4 v;
            v.x = W[(kbase + k4 * 4 + 0) * 128 + c0 + c];
            v.y = W[(kbase + k4 * 4 + 1) * 128 + c0 + c];
            v.z = W[(kbase + k4 * 4 + 2) * 128 + c0 + c];
            v.w = W[(kbase + k4 * 4 + 3) * 128 + c0 + c];
            *(float4*)&wt[c][k4 * 4] = v;
        }
        __syncthreads();
        #pragma unroll 4
        for (int k4 = 0; k4 < 16; ++k4) {
            float4 wv[4], xv[8];
            #pragma unroll
            for (int j = 0; j < 4; ++j) wv[j] = *(const float4*)&wt[colT + 16 * j][k4 * 4];
            #pragma unroll
            for (int i = 0; i < 8; ++i) xv[i] = *(const float4*)&xs[rowT + 8 * i][k4 * 4];
            #pragma unroll
            for (int j = 0; j < 4; ++j)
                #pragma unroll
                for (int i = 0; i < 8; ++i)
                    acc[j][i] += wv[j].x * xv[i].x + wv[j].y * xv[i].y
                               + wv[j].z * xv[i].z + wv[j].w * xv[i].w;
        }
        __syncthreads();
    }

    // epilogue: store h, fused per-head scores
    #pragma unroll
    for (int i = 0; i < 8; ++i) {
        const int row = r0 + rowT + 8 * i;
        float vs = 0.f, vd = 0.f;
        #pragma unroll
        for (int j = 0; j < 4; ++j) {
            const int c = c0 + colT + 16 * j;
            const float a = acc[j][i];
            vs += a * a_src[c];
            vd += a * a_dst[c];
            if (row < N_NODES) h[(size_t)row * 128 + c] = a;
        }
        #pragma unroll
        for (int off = 8; off >= 1; off >>= 1) {
            vs += __shfl_xor(vs, off, 64);
            vd += __shfl_xor(vd, off, 64);
        }
        if (colT == 0 && row < N_NODES) {
            s_src[row * 2 + half] = vs;
            s_dst[row * 2 + half] = vd;
        }
    }
}

// ================= layer 2 GEMM: g = h2 @ W2  [N,128]x[128,32] ================
// grid = ceil(N/128) ; block 128 = (8 colT, 16 rowT)
// tile 128 rows x 32 cols; thread: 4 cols (c = colT + 8j), 8 rows (r = rowT + 16i)
__global__ __launch_bounds__(128) void gemm2_tiled(
    const float* __restrict__ h2, const float* __restrict__ W,
    const float* __restrict__ a_src, const float* __restrict__ a_dst,
    float* __restrict__ g, float* __restrict__ s_src, float* __restrict__ s_dst)
{
    __shared__ float xs[128][68];
    __shared__ float wt[32][68];
    const int tid  = threadIdx.x;
    const int colT = tid & 7;
    const int rowT = tid >> 3;
    const int r0   = blockIdx.x * 128;

    float acc[4][8];
    #pragma unroll
    for (int j = 0; j < 4; ++j)
        #pragma unroll
        for (int i = 0; i < 8; ++i) acc[j][i] = 0.f;

    for (int kc = 0; kc < 2; ++kc) {
        const int kbase = kc * 64;
        // stage xs: 128 rows x 16 quads
        #pragma unroll
        for (int it = 0; it < 16; ++it) {
            int q = it * 128 + tid;
            int row = q >> 4, k4 = q & 15;
            float4 v = make_float4(0.f, 0.f, 0.f, 0.f);
            if (r0 + row < N_NODES)
                v = *(const float4*)&h2[(size_t)(r0 + row) * 128 + kbase + k4 * 4];
            *(float4*)&xs[row][k4 * 4] = v;
        }
        // stage wt[c][k] = W[kbase+k][c]: 32 c x 16 quads
        #pragma unroll
        for (int it = 0; it < 4; ++it) {
            int q = it * 128 + tid;
            int c = q & 31, k4 = q >> 5;
            float4 v;
            v.x = W[(kbase + k4 * 4 + 0) * 32 + c];
            v.y = W[(kbase + k4 * 4 + 1) * 32 + c];
            v.z = W[(kbase + k4 * 4 + 2) * 32 + c];
            v.w = W[(kbase + k4 * 4 + 3) * 32 + c];
            *(float4*)&wt[c][k4 * 4] = v;
        }
        __syncthreads();
        #pragma unroll 4
        for (int k4 = 0; k4 < 16; ++k4) {
            float4 wv[4], xv[8];
            #pragma unroll
            for (int j = 0; j < 4; ++j) wv[j] = *(const float4*)&wt[colT + 8 * j][k4 * 4];
            #pragma unroll
            for (int i = 0; i < 8; ++i) xv[i] = *(const float4*)&xs[rowT + 16 * i][k4 * 4];
            #pragma unroll
            for (int j = 0; j < 4; ++j)
                #pragma unroll
                for (int i = 0; i < 8; ++i)
                    acc[j][i] += wv[j].x * xv[i].x + wv[j].y * xv[i].y
                               + wv[j].z * xv[i].z + wv[j].w * xv[i].w;
        }
        __syncthreads();
    }

    #pragma unroll
    for (int i = 0; i < 8; ++i) {
        const int row = r0 + rowT + 16 * i;
        float vs = 0.f, vd = 0.f;
        #pragma unroll
        for (int j = 0; j < 4; ++j) {
            const int c = colT + 8 * j;
            const float a = acc[j][i];
            vs += a * a_src[c];
            vd += a * a_dst[c];
            if (row < N_NODES) g[(size_t)row * 32 + c] = a;
        }
        #pragma unroll
        for (int off = 4; off >= 1; off >>= 1) {
            vs += __shfl_xor(vs, off, 64);
            vd += __shfl_xor(vd, off, 64);
        }
        if (colT == 0 && row < N_NODES) {
            s_src[row] = vs;
            s_dst[row] = vd;
        }
    }
}

// ---------- CSR build: histogram ----------
__global__ void hist_kernel(const int* __restrict__ edst, int* __restrict__ deg)
{
    int e = blockIdx.x * blockDim.x + threadIdx.x;
    if (e >= E_TOT) return;
    int d = (e < N_EDGES) ? edst[e] : (e - N_EDGES);
    atomicAdd(&deg[d], 1);
}

// ---------- CSR build: single-block exclusive scan (N=50000) ----------
__global__ __launch_bounds__(1024) void scan_kernel(
    const int* __restrict__ deg, int* __restrict__ offsets, int* __restrict__ cursor)
{
    __shared__ int buf[1024];
    __shared__ int s_carry;
    const int t = threadIdx.x;
    if (t == 0) s_carry = 0;
    __syncthreads();
    for (int base = 0; base < N_NODES; base += 1024) {
        int i = base + t;
        int v = (i < N_NODES) ? deg[i] : 0;
        buf[t] = v;
        __syncthreads();
        #pragma unroll
        for (int off = 1; off < 1024; off <<= 1) {
            int xx = (t >= off) ? buf[t - off] : 0;
            __syncthreads();
            buf[t] += xx;
            __syncthreads();
        }
        int carry = s_carry;
        if (i < N_NODES) {
            int excl = carry + buf[t] - v;
            offsets[i] = excl;
            cursor[i]  = excl;
        }
        __syncthreads();
        if (t == 0) s_carry = carry + buf[1023];
        __syncthreads();
    }
    if (t == 0) offsets[N_NODES] = s_carry;
}

// ---------- CSR build: scatter src ids by destination ----------
__global__ void scatter_kernel(const int* __restrict__ esrc, const int* __restrict__ edst,
                               int* __restrict__ cursor, int* __restrict__ csr_src)
{
    int e = blockIdx.x * blockDim.x + threadIdx.x;
    if (e >= E_TOT) return;
    int s, d;
    if (e < N_EDGES) { s = esrc[e]; d = edst[e]; } else { s = d = e - N_EDGES; }
    int pos = atomicAdd(&cursor[d], 1);
    csr_src[pos] = s;
}

// ---------- layer 1 fused: online softmax + aggregate + bias + ELU ----------
__global__ __launch_bounds__(256) void fused_agg1_kernel(
    const int* __restrict__ csr_src, const int* __restrict__ offsets,
    const float* __restrict__ s_src, const float* __restrict__ s_dst,
    const float* __restrict__ h, const float* __restrict__ b,
    float* __restrict__ h2)
{
    const int wid  = threadIdx.x >> 6;
    const int lane = threadIdx.x & 63;
    const int d = blockIdx.x * 4 + wid;
    if (d >= N_NODES) return;
    const int beg = offsets[d], end = offsets[d + 1];
    const float sd0 = s_dst[d * 2], sd1 = s_dst[d * 2 + 1];
    float m0 = -INFINITY, m1 = -INFINITY;
    float den0 = 0.f, den1 = 0.f, acc0 = 0.f, acc1 = 0.f;
    for (int i = beg; i < end; ++i) {
        const int s = csr_src[i];
        float v0 = s_src[s * 2]     + sd0;  v0 = v0 > 0.f ? v0 : 0.2f * v0;
        float v1 = s_src[s * 2 + 1] + sd1;  v1 = v1 > 0.f ? v1 : 0.2f * v1;
        const float nm0 = fmaxf(m0, v0), nm1 = fmaxf(m1, v1);
        const float sc0 = __expf(m0 - nm0), sc1 = __expf(m1 - nm1);
        const float e0  = __expf(v0 - nm0), e1  = __expf(v1 - nm1);
        const float hv0 = h[s * 128 + lane];
        const float hv1 = h[s * 128 + 64 + lane];
        den0 = den0 * sc0 + e0;
        den1 = den1 * sc1 + e1;
        acc0 = acc0 * sc0 + e0 * hv0;
        acc1 = acc1 * sc1 + e1 * hv1;
        m0 = nm0; m1 = nm1;
    }
    float o0 = acc0 / den0 + b[lane];
    float o1 = acc1 / den1 + b[64 + lane];
    o0 = o0 > 0.f ? o0 : expm1f(o0);
    o1 = o1 > 0.f ? o1 : expm1f(o1);
    h2[d * 128 + lane]      = o0;
    h2[d * 128 + 64 + lane] = o1;
}

// ---------- layer 2 fused: online softmax + aggregate + bias -> out ----------
__global__ __launch_bounds__(256) void fused_agg2_kernel(
    const int* __restrict__ csr_src, const int* __restrict__ offsets,
    const float* __restrict__ s_src, const float* __restrict__ s_dst,
    const float* __restrict__ g, const float* __restrict__ b,
    float* __restrict__ out)
{
    const int grp  = threadIdx.x >> 5;
    const int lane = threadIdx.x & 31;
    const int d = blockIdx.x * 8 + grp;
    if (d >= N_NODES) return;
    const int beg = offsets[d], end = offsets[d + 1];
    const float sd = s_dst[d];
    float m = -INFINITY, den = 0.f, acc = 0.f;
    for (int i = beg; i < end; ++i) {
        const int s = csr_src[i];
        float v = s_src[s] + sd;  v = v > 0.f ? v : 0.2f * v;
        const float nm = fmaxf(m, v);
        const float sc = __expf(m - nm);
        const float e  = __expf(v - nm);
        const float gv = g[s * 32 + lane];
        den = den * sc + e;
        acc = acc * sc + e * gv;
        m = nm;
    }
    out[d * 32 + lane] = acc / den + b[lane];
}

extern "C" void kernel_launch(void* const* d_in, const int* in_sizes, int n_in,
                              void* d_out, int out_size, void* d_ws, size_t ws_size,
                              hipStream_t stream)
{
    const float* x   = (const float*)d_in[0];
    const int*   ei  = (const int*)d_in[1];     // [2, E] int32: row0 = src, row1 = dst
    const float* W1  = (const float*)d_in[2];
    const float* a1s = (const float*)d_in[3];
    const float* a1d = (const float*)d_in[4];
    const float* b1  = (const float*)d_in[5];
    const float* W2  = (const float*)d_in[6];
    const float* a2s = (const float*)d_in[7];
    const float* a2d = (const float*)d_in[8];
    const float* b2  = (const float*)d_in[9];
    float* out = (float*)d_out;

    const int* esrc = ei;
    const int* edst = ei + N_EDGES;

    // -------- workspace layout --------
    float* ws = (float*)d_ws;
    float* h1  = ws;                                 // N*128
    float* h2  = h1  + (size_t)N_NODES * 128;        // N*128
    float* s1s = h2  + (size_t)N_NODES * 128;        // 2N
    float* s1d = s1s + 2 * N_NODES;                  // 2N
    float* s2s = s1d + 2 * N_NODES;                  // N
    float* s2d = s2s + N_NODES;                      // N
    int* deg     = (int*)(s2d + N_NODES);            // N
    int* offsets = deg + N_NODES;                    // N+1
    int* cursor  = offsets + N_NODES + 1;            // N
    int* csr_src = cursor + N_NODES;                 // E_TOT
    float* g2 = h1;                                  // N*32 (h1 dead after fused_agg1)

    // -------- CSR build --------
    hipMemsetAsync(deg, 0, (size_t)N_NODES * 4, stream);
    hist_kernel<<<(E_TOT + 255) / 256, 256, 0, stream>>>(edst, deg);
    scan_kernel<<<1, 1024, 0, stream>>>(deg, offsets, cursor);
    scatter_kernel<<<(E_TOT + 255) / 256, 256, 0, stream>>>(esrc, edst, cursor, csr_src);

    // -------- layer 1 --------
    gemm1_tiled<<<((N_NODES + 63) / 64) * 2, 128, 0, stream>>>(x, W1, a1s, a1d, h1, s1s, s1d);
    fused_agg1_kernel<<<(N_NODES + 3) / 4, 256, 0, stream>>>(
        csr_src, offsets, s1s, s1d, h1, b1, h2);

    // -------- layer 2 --------
    gemm2_tiled<<<(N_NODES + 127) / 128, 128, 0, stream>>>(h2, W2, a2s, a2d, g2, s2s, s2d);
    fused_agg2_kernel<<<(N_NODES + 7) / 8, 256, 0, stream>>>(
        csr_src, offsets, s2s, s2d, g2, b2, out);
}

// Round 5
// 365.361 us; speedup vs baseline: 2.0982x; 1.1294x over previous
//
#include <hip/hip_runtime.h>
#include <math.h>

#define N_NODES 50000
#define N_EDGES 800000
#define E_TOT   (N_EDGES + N_NODES)   // 850000 edges incl. self loops

__device__ __forceinline__ float bcast_f(float v, int srclane) {
    return __uint_as_float(__builtin_amdgcn_readlane(__float_as_uint(v), srclane));
}

// ================= layer 1 GEMM: h1 = x @ W1  [N,128]x[128,128] ================
__global__ __launch_bounds__(128) void gemm1_tiled(
    const float* __restrict__ x, const float* __restrict__ W,
    const float* __restrict__ a_src, const float* __restrict__ a_dst,
    float* __restrict__ h, float* __restrict__ s_src, float* __restrict__ s_dst)
{
    __shared__ float xs[64][68];
    __shared__ float wt[64][68];
    const int tid  = threadIdx.x;
    const int colT = tid & 15;
    const int rowT = tid >> 4;
    const int half = blockIdx.x & 1;          // head
    const int r0   = (blockIdx.x >> 1) * 64;
    const int c0   = half * 64;

    float acc[4][8];
    #pragma unroll
    for (int j = 0; j < 4; ++j)
        #pragma unroll
        for (int i = 0; i < 8; ++i) acc[j][i] = 0.f;

    for (int kc = 0; kc < 2; ++kc) {
        const int kbase = kc * 64;
        #pragma unroll
        for (int it = 0; it < 8; ++it) {
            int q = it * 128 + tid;
            int row = q >> 4, k4 = q & 15;
            float4 v = make_float4(0.f, 0.f, 0.f, 0.f);
            if (r0 + row < N_NODES)
                v = *(const float4*)&x[(size_t)(r0 + row) * 128 + kbase + k4 * 4];
            *(float4*)&xs[row][k4 * 4] = v;
        }
        #pragma unroll
        for (int it = 0; it < 8; ++it) {
            int q = it * 128 + tid;
            int c = q & 63, k4 = q >> 6;
            float4 v;
            v.x = W[(kbase + k4 * 4 + 0) * 128 + c0 + c];
            v.y = W[(kbase + k4 * 4 + 1) * 128 + c0 + c];
            v.z = W[(kbase + k4 * 4 + 2) * 128 + c0 + c];
            v.w = W[(kbase + k4 * 4 + 3) * 128 + c0 + c];
            *(float4*)&wt[c][k4 * 4] = v;
        }
        __syncthreads();
        #pragma unroll 4
        for (int k4 = 0; k4 < 16; ++k4) {
            float4 wv[4], xv[8];
            #pragma unroll
            for (int j = 0; j < 4; ++j) wv[j] = *(const float4*)&wt[colT + 16 * j][k4 * 4];
            #pragma unroll
            for (int i = 0; i < 8; ++i) xv[i] = *(const float4*)&xs[rowT + 8 * i][k4 * 4];
            #pragma unroll
            for (int j = 0; j < 4; ++j)
                #pragma unroll
                for (int i = 0; i < 8; ++i)
                    acc[j][i] += wv[j].x * xv[i].x + wv[j].y * xv[i].y
                               + wv[j].z * xv[i].z + wv[j].w * xv[i].w;
        }
        __syncthreads();
    }

    #pragma unroll
    for (int i = 0; i < 8; ++i) {
        const int row = r0 + rowT + 8 * i;
        float vs = 0.f, vd = 0.f;
        #pragma unroll
        for (int j = 0; j < 4; ++j) {
            const int c = c0 + colT + 16 * j;
            const float a = acc[j][i];
            vs += a * a_src[c];
            vd += a * a_dst[c];
            if (row < N_NODES) h[(size_t)row * 128 + c] = a;
        }
        #pragma unroll
        for (int off = 8; off >= 1; off >>= 1) {
            vs += __shfl_xor(vs, off, 64);
            vd += __shfl_xor(vd, off, 64);
        }
        if (colT == 0 && row < N_NODES) {
            s_src[row * 2 + half] = vs;
            s_dst[row * 2 + half] = vd;
        }
    }
}

// ================= layer 2 GEMM: g = h2 @ W2  [N,128]x[128,32] ================
__global__ __launch_bounds__(128) void gemm2_tiled(
    const float* __restrict__ h2, const float* __restrict__ W,
    const float* __restrict__ a_src, const float* __restrict__ a_dst,
    float* __restrict__ g, float* __restrict__ s_src, float* __restrict__ s_dst)
{
    __shared__ float xs[128][68];
    __shared__ float wt[32][68];
    const int tid  = threadIdx.x;
    const int colT = tid & 7;
    const int rowT = tid >> 3;
    const int r0   = blockIdx.x * 128;

    float acc[4][8];
    #pragma unroll
    for (int j = 0; j < 4; ++j)
        #pragma unroll
        for (int i = 0; i < 8; ++i) acc[j][i] = 0.f;

    for (int kc = 0; kc < 2; ++kc) {
        const int kbase = kc * 64;
        #pragma unroll
        for (int it = 0; it < 16; ++it) {
            int q = it * 128 + tid;
            int row = q >> 4, k4 = q & 15;
            float4 v = make_float4(0.f, 0.f, 0.f, 0.f);
            if (r0 + row < N_NODES)
                v = *(const float4*)&h2[(size_t)(r0 + row) * 128 + kbase + k4 * 4];
            *(float4*)&xs[row][k4 * 4] = v;
        }
        #pragma unroll
        for (int it = 0; it < 4; ++it) {
            int q = it * 128 + tid;
            int c = q & 31, k4 = q >> 5;
            float4 v;
            v.x = W[(kbase + k4 * 4 + 0) * 32 + c];
            v.y = W[(kbase + k4 * 4 + 1) * 32 + c];
            v.z = W[(kbase + k4 * 4 + 2) * 32 + c];
            v.w = W[(kbase + k4 * 4 + 3) * 32 + c];
            *(float4*)&wt[c][k4 * 4] = v;
        }
        __syncthreads();
        #pragma unroll 4
        for (int k4 = 0; k4 < 16; ++k4) {
            float4 wv[4], xv[8];
            #pragma unroll
            for (int j = 0; j < 4; ++j) wv[j] = *(const float4*)&wt[colT + 8 * j][k4 * 4];
            #pragma unroll
            for (int i = 0; i < 8; ++i) xv[i] = *(const float4*)&xs[rowT + 16 * i][k4 * 4];
            #pragma unroll
            for (int j = 0; j < 4; ++j)
                #pragma unroll
                for (int i = 0; i < 8; ++i)
                    acc[j][i] += wv[j].x * xv[i].x + wv[j].y * xv[i].y
                               + wv[j].z * xv[i].z + wv[j].w * xv[i].w;
        }
        __syncthreads();
    }

    #pragma unroll
    for (int i = 0; i < 8; ++i) {
        const int row = r0 + rowT + 16 * i;
        float vs = 0.f, vd = 0.f;
        #pragma unroll
        for (int j = 0; j < 4; ++j) {
            const int c = colT + 8 * j;
            const float a = acc[j][i];
            vs += a * a_src[c];
            vd += a * a_dst[c];
            if (row < N_NODES) g[(size_t)row * 32 + c] = a;
        }
        #pragma unroll
        for (int off = 4; off >= 1; off >>= 1) {
            vs += __shfl_xor(vs, off, 64);
            vd += __shfl_xor(vd, off, 64);
        }
        if (colT == 0 && row < N_NODES) {
            s_src[row] = vs;
            s_dst[row] = vd;
        }
    }
}

// ---------- CSR build ----------
__global__ void hist_kernel(const int* __restrict__ edst, int* __restrict__ deg)
{
    int e = blockIdx.x * blockDim.x + threadIdx.x;
    if (e >= E_TOT) return;
    int d = (e < N_EDGES) ? edst[e] : (e - N_EDGES);
    atomicAdd(&deg[d], 1);
}

__global__ __launch_bounds__(1024) void scan_kernel(
    const int* __restrict__ deg, int* __restrict__ offsets, int* __restrict__ cursor)
{
    __shared__ int buf[1024];
    __shared__ int s_carry;
    const int t = threadIdx.x;
    if (t == 0) s_carry = 0;
    __syncthreads();
    for (int base = 0; base < N_NODES; base += 1024) {
        int i = base + t;
        int v = (i < N_NODES) ? deg[i] : 0;
        buf[t] = v;
        __syncthreads();
        #pragma unroll
        for (int off = 1; off < 1024; off <<= 1) {
            int xx = (t >= off) ? buf[t - off] : 0;
            __syncthreads();
            buf[t] += xx;
            __syncthreads();
        }
        int carry = s_carry;
        if (i < N_NODES) {
            int excl = carry + buf[t] - v;
            offsets[i] = excl;
            cursor[i]  = excl;
        }
        __syncthreads();
        if (t == 0) s_carry = carry + buf[1023];
        __syncthreads();
    }
    if (t == 0) offsets[N_NODES] = s_carry;
}

__global__ void scatter_kernel(const int* __restrict__ esrc, const int* __restrict__ edst,
                               int* __restrict__ cursor, int* __restrict__ csr_src)
{
    int e = blockIdx.x * blockDim.x + threadIdx.x;
    if (e >= E_TOT) return;
    int s, d;
    if (e < N_EDGES) { s = esrc[e]; d = edst[e]; } else { s = d = e - N_EDGES; }
    int pos = atomicAdd(&cursor[d], 1);
    csr_src[pos] = s;
}

// ---------- layer 1 fused: chunked softmax + aggregate + bias + ELU ----------
// one wave per destination; lane owns one edge's score per 64-edge chunk;
// readlane (uniform loop index -> defined) broadcasts (src, e0, e1)
__global__ __launch_bounds__(256) void fused_agg1_kernel(
    const int* __restrict__ csr_src, const int* __restrict__ offsets,
    const float* __restrict__ s_src, const float* __restrict__ s_dst,
    const float* __restrict__ h, const float* __restrict__ b,
    float* __restrict__ h2)
{
    const int wid  = threadIdx.x >> 6;
    const int lane = threadIdx.x & 63;
    const int d = blockIdx.x * 4 + wid;
    if (d >= N_NODES) return;
    const int beg = offsets[d], end = offsets[d + 1];
    const float sd0 = s_dst[d * 2], sd1 = s_dst[d * 2 + 1];
    float m0 = -1e30f, m1 = -1e30f;
    float den0 = 0.f, den1 = 0.f, acc0 = 0.f, acc1 = 0.f;

    for (int pos = beg; pos < end; pos += 64) {
        const int n = min(64, end - pos);
        int s = 0;
        float v0 = -1e30f, v1 = -1e30f;
        if (lane < n) {
            s = csr_src[pos + lane];
            const float2 ss = *(const float2*)&s_src[s * 2];
            v0 = ss.x + sd0;  v0 = v0 > 0.f ? v0 : 0.2f * v0;
            v1 = ss.y + sd1;  v1 = v1 > 0.f ? v1 : 0.2f * v1;
        }
        // chunk max
        float cm0 = v0, cm1 = v1;
        #pragma unroll
        for (int off = 32; off >= 1; off >>= 1) {
            cm0 = fmaxf(cm0, __shfl_xor(cm0, off, 64));
            cm1 = fmaxf(cm1, __shfl_xor(cm1, off, 64));
        }
        const float nm0 = fmaxf(m0, cm0), nm1 = fmaxf(m1, cm1);
        const float sc0 = __expf(m0 - nm0), sc1 = __expf(m1 - nm1);
        acc0 *= sc0; den0 *= sc0;
        acc1 *= sc1; den1 *= sc1;
        m0 = nm0; m1 = nm1;
        const float e0 = (lane < n) ? __expf(v0 - nm0) : 0.f;
        const float e1 = (lane < n) ? __expf(v1 - nm1) : 0.f;
        float t0 = e0, t1 = e1;
        #pragma unroll
        for (int off = 32; off >= 1; off >>= 1) {
            t0 += __shfl_xor(t0, off, 64);
            t1 += __shfl_xor(t1, off, 64);
        }
        den0 += t0; den1 += t1;
        // gather + accumulate (readlane: lane index is the uniform loop counter)
        for (int i = 0; i < n; ++i) {
            const int   si = __builtin_amdgcn_readlane(s, i);
            const float a0 = bcast_f(e0, i);
            const float a1 = bcast_f(e1, i);
            const float* hp = h + (size_t)si * 128;
            acc0 += a0 * hp[lane];
            acc1 += a1 * hp[64 + lane];
        }
    }
    float o0 = acc0 / den0 + b[lane];
    float o1 = acc1 / den1 + b[64 + lane];
    o0 = o0 > 0.f ? o0 : expm1f(o0);
    o1 = o1 > 0.f ? o1 : expm1f(o1);
    h2[d * 128 + lane]      = o0;
    h2[d * 128 + 64 + lane] = o1;
}

// ---------- layer 2 fused: chunked softmax + aggregate + bias -> out ----------
// one 32-lane group per destination; 32-edge chunks.
// Broadcast uses __shfl (ds_bpermute, per-lane src index) because the source
// lane (i + halfbase) is NOT wave-uniform -> readlane would be UB here.
__global__ __launch_bounds__(256) void fused_agg2_kernel(
    const int* __restrict__ csr_src, const int* __restrict__ offsets,
    const float* __restrict__ s_src, const float* __restrict__ s_dst,
    const float* __restrict__ g, const float* __restrict__ b,
    float* __restrict__ out)
{
    const int grp      = threadIdx.x >> 5;
    const int lane     = threadIdx.x & 31;
    const int halfbase = threadIdx.x & 32;   // lane offset of this group within its wave
    const int d = blockIdx.x * 8 + grp;
    if (d >= N_NODES) return;
    const int beg = offsets[d], end = offsets[d + 1];
    const float sd = s_dst[d];
    float m = -1e30f, den = 0.f, acc = 0.f;

    for (int pos = beg; pos < end; pos += 32) {
        const int n = min(32, end - pos);
        int s = 0;
        float v = -1e30f;
        if (lane < n) {
            s = csr_src[pos + lane];
            v = s_src[s] + sd;  v = v > 0.f ? v : 0.2f * v;
        }
        float cm = v;
        #pragma unroll
        for (int off = 16; off >= 1; off >>= 1)
            cm = fmaxf(cm, __shfl_xor(cm, off, 32));
        const float nm = fmaxf(m, cm);
        const float sc = __expf(m - nm);
        acc *= sc; den *= sc;
        m = nm;
        const float e = (lane < n) ? __expf(v - nm) : 0.f;
        float t = e;
        #pragma unroll
        for (int off = 16; off >= 1; off >>= 1)
            t += __shfl_xor(t, off, 32);
        den += t;
        for (int i = 0; i < n; ++i) {
            const int   si = __shfl(s, i + halfbase, 64);   // bpermute: per-lane src ok
            const float a  = __shfl(e, i + halfbase, 64);
            acc += a * g[(size_t)si * 32 + lane];
        }
    }
    out[d * 32 + lane] = acc / den + b[lane];
}

extern "C" void kernel_launch(void* const* d_in, const int* in_sizes, int n_in,
                              void* d_out, int out_size, void* d_ws, size_t ws_size,
                              hipStream_t stream)
{
    const float* x   = (const float*)d_in[0];
    const int*   ei  = (const int*)d_in[1];     // [2, E] int32: row0 = src, row1 = dst
    const float* W1  = (const float*)d_in[2];
    const float* a1s = (const float*)d_in[3];
    const float* a1d = (const float*)d_in[4];
    const float* b1  = (const float*)d_in[5];
    const float* W2  = (const float*)d_in[6];
    const float* a2s = (const float*)d_in[7];
    const float* a2d = (const float*)d_in[8];
    const float* b2  = (const float*)d_in[9];
    float* out = (float*)d_out;

    const int* esrc = ei;
    const int* edst = ei + N_EDGES;

    // -------- workspace layout --------
    float* ws = (float*)d_ws;
    float* h1  = ws;                                 // N*128
    float* h2  = h1  + (size_t)N_NODES * 128;        // N*128
    float* s1s = h2  + (size_t)N_NODES * 128;        // 2N
    float* s1d = s1s + 2 * N_NODES;                  // 2N
    float* s2s = s1d + 2 * N_NODES;                  // N
    float* s2d = s2s + N_NODES;                      // N
    int* deg     = (int*)(s2d + N_NODES);            // N
    int* offsets = deg + N_NODES;                    // N+1
    int* cursor  = offsets + N_NODES + 1;            // N
    int* csr_src = cursor + N_NODES;                 // E_TOT
    float* g2 = h1;                                  // N*32 (h1 dead after fused_agg1)

    // -------- CSR build --------
    hipMemsetAsync(deg, 0, (size_t)N_NODES * 4, stream);
    hist_kernel<<<(E_TOT + 255) / 256, 256, 0, stream>>>(edst, deg);
    scan_kernel<<<1, 1024, 0, stream>>>(deg, offsets, cursor);
    scatter_kernel<<<(E_TOT + 255) / 256, 256, 0, stream>>>(esrc, edst, cursor, csr_src);

    // -------- layer 1 --------
    gemm1_tiled<<<((N_NODES + 63) / 64) * 2, 128, 0, stream>>>(x, W1, a1s, a1d, h1, s1s, s1d);
    fused_agg1_kernel<<<(N_NODES + 3) / 4, 256, 0, stream>>>(
        csr_src, offsets, s1s, s1d, h1, b1, h2);

    // -------- layer 2 --------
    gemm2_tiled<<<(N_NODES + 127) / 128, 128, 0, stream>>>(h2, W2, a2s, a2d, g2, s2s, s2d);
    fused_agg2_kernel<<<(N_NODES + 7) / 8, 256, 0, stream>>>(
        csr_src, offsets, s2s, s2d, g2, b2, out);
}

// Round 6
// 292.858 us; speedup vs baseline: 2.6177x; 1.2476x over previous
//
#include <hip/hip_runtime.h>
#include <math.h>

#define N_NODES 50000
#define N_EDGES 800000
#define E_TOT   (N_EDGES + N_NODES)   // 850000 edges incl. self loops
#define SCAN_BLK 1024
#define SCAN_NB  ((N_NODES + SCAN_BLK - 1) / SCAN_BLK)   // 49

__device__ __forceinline__ float bcast_f(float v, int srclane) {
    return __uint_as_float(__builtin_amdgcn_readlane(__float_as_uint(v), srclane));
}

// ================= layer 1 GEMM: h1 = x @ W1  [N,128]x[128,128] ================
__global__ __launch_bounds__(128) void gemm1_tiled(
    const float* __restrict__ x, const float* __restrict__ W,
    const float* __restrict__ a_src, const float* __restrict__ a_dst,
    float* __restrict__ h, float* __restrict__ s_src, float* __restrict__ s_dst)
{
    __shared__ float xs[64][68];
    __shared__ float wt[64][68];
    const int tid  = threadIdx.x;
    const int colT = tid & 15;
    const int rowT = tid >> 4;
    const int half = blockIdx.x & 1;          // head
    const int r0   = (blockIdx.x >> 1) * 64;
    const int c0   = half * 64;

    float acc[4][8];
    #pragma unroll
    for (int j = 0; j < 4; ++j)
        #pragma unroll
        for (int i = 0; i < 8; ++i) acc[j][i] = 0.f;

    for (int kc = 0; kc < 2; ++kc) {
        const int kbase = kc * 64;
        #pragma unroll
        for (int it = 0; it < 8; ++it) {
            int q = it * 128 + tid;
            int row = q >> 4, k4 = q & 15;
            float4 v = make_float4(0.f, 0.f, 0.f, 0.f);
            if (r0 + row < N_NODES)
                v = *(const float4*)&x[(size_t)(r0 + row) * 128 + kbase + k4 * 4];
            *(float4*)&xs[row][k4 * 4] = v;
        }
        #pragma unroll
        for (int it = 0; it < 8; ++it) {
            int q = it * 128 + tid;
            int c = q & 63, k4 = q >> 6;
            float4 v;
            v.x = W[(kbase + k4 * 4 + 0) * 128 + c0 + c];
            v.y = W[(kbase + k4 * 4 + 1) * 128 + c0 + c];
            v.z = W[(kbase + k4 * 4 + 2) * 128 + c0 + c];
            v.w = W[(kbase + k4 * 4 + 3) * 128 + c0 + c];
            *(float4*)&wt[c][k4 * 4] = v;
        }
        __syncthreads();
        #pragma unroll 4
        for (int k4 = 0; k4 < 16; ++k4) {
            float4 wv[4], xv[8];
            #pragma unroll
            for (int j = 0; j < 4; ++j) wv[j] = *(const float4*)&wt[colT + 16 * j][k4 * 4];
            #pragma unroll
            for (int i = 0; i < 8; ++i) xv[i] = *(const float4*)&xs[rowT + 8 * i][k4 * 4];
            #pragma unroll
            for (int j = 0; j < 4; ++j)
                #pragma unroll
                for (int i = 0; i < 8; ++i)
                    acc[j][i] += wv[j].x * xv[i].x + wv[j].y * xv[i].y
                               + wv[j].z * xv[i].z + wv[j].w * xv[i].w;
        }
        __syncthreads();
    }

    #pragma unroll
    for (int i = 0; i < 8; ++i) {
        const int row = r0 + rowT + 8 * i;
        float vs = 0.f, vd = 0.f;
        #pragma unroll
        for (int j = 0; j < 4; ++j) {
            const int c = c0 + colT + 16 * j;
            const float a = acc[j][i];
            vs += a * a_src[c];
            vd += a * a_dst[c];
            if (row < N_NODES) h[(size_t)row * 128 + c] = a;
        }
        #pragma unroll
        for (int off = 8; off >= 1; off >>= 1) {
            vs += __shfl_xor(vs, off, 64);
            vd += __shfl_xor(vd, off, 64);
        }
        if (colT == 0 && row < N_NODES) {
            s_src[row * 2 + half] = vs;
            s_dst[row * 2 + half] = vd;
        }
    }
}

// ================= layer 2 GEMM: g = h2 @ W2  [N,128]x[128,32] ================
__global__ __launch_bounds__(128) void gemm2_tiled(
    const float* __restrict__ h2, const float* __restrict__ W,
    const float* __restrict__ a_src, const float* __restrict__ a_dst,
    float* __restrict__ g, float* __restrict__ s_src, float* __restrict__ s_dst)
{
    __shared__ float xs[128][68];
    __shared__ float wt[32][68];
    const int tid  = threadIdx.x;
    const int colT = tid & 7;
    const int rowT = tid >> 3;
    const int r0   = blockIdx.x * 128;

    float acc[4][8];
    #pragma unroll
    for (int j = 0; j < 4; ++j)
        #pragma unroll
        for (int i = 0; i < 8; ++i) acc[j][i] = 0.f;

    for (int kc = 0; kc < 2; ++kc) {
        const int kbase = kc * 64;
        #pragma unroll
        for (int it = 0; it < 16; ++it) {
            int q = it * 128 + tid;
            int row = q >> 4, k4 = q & 15;
            float4 v = make_float4(0.f, 0.f, 0.f, 0.f);
            if (r0 + row < N_NODES)
                v = *(const float4*)&h2[(size_t)(r0 + row) * 128 + kbase + k4 * 4];
            *(float4*)&xs[row][k4 * 4] = v;
        }
        #pragma unroll
        for (int it = 0; it < 4; ++it) {
            int q = it * 128 + tid;
            int c = q & 31, k4 = q >> 5;
            float4 v;
            v.x = W[(kbase + k4 * 4 + 0) * 32 + c];
            v.y = W[(kbase + k4 * 4 + 1) * 32 + c];
            v.z = W[(kbase + k4 * 4 + 2) * 32 + c];
            v.w = W[(kbase + k4 * 4 + 3) * 32 + c];
            *(float4*)&wt[c][k4 * 4] = v;
        }
        __syncthreads();
        #pragma unroll 4
        for (int k4 = 0; k4 < 16; ++k4) {
            float4 wv[4], xv[8];
            #pragma unroll
            for (int j = 0; j < 4; ++j) wv[j] = *(const float4*)&wt[colT + 8 * j][k4 * 4];
            #pragma unroll
            for (int i = 0; i < 8; ++i) xv[i] = *(const float4*)&xs[rowT + 16 * i][k4 * 4];
            #pragma unroll
            for (int j = 0; j < 4; ++j)
                #pragma unroll
                for (int i = 0; i < 8; ++i)
                    acc[j][i] += wv[j].x * xv[i].x + wv[j].y * xv[i].y
                               + wv[j].z * xv[i].z + wv[j].w * xv[i].w;
        }
        __syncthreads();
    }

    #pragma unroll
    for (int i = 0; i < 8; ++i) {
        const int row = r0 + rowT + 16 * i;
        float vs = 0.f, vd = 0.f;
        #pragma unroll
        for (int j = 0; j < 4; ++j) {
            const int c = colT + 8 * j;
            const float a = acc[j][i];
            vs += a * a_src[c];
            vd += a * a_dst[c];
            if (row < N_NODES) g[(size_t)row * 32 + c] = a;
        }
        #pragma unroll
        for (int off = 4; off >= 1; off >>= 1) {
            vs += __shfl_xor(vs, off, 64);
            vd += __shfl_xor(vd, off, 64);
        }
        if (colT == 0 && row < N_NODES) {
            s_src[row] = vs;
            s_dst[row] = vd;
        }
    }
}

// ---------- CSR build ----------
__global__ void hist_kernel(const int* __restrict__ edst, int* __restrict__ deg)
{
    int e = blockIdx.x * blockDim.x + threadIdx.x;
    if (e >= E_TOT) return;
    int d = (e < N_EDGES) ? edst[e] : (e - N_EDGES);
    atomicAdd(&deg[d], 1);
}

// Phase A: per-block local exclusive scan + block total
__global__ __launch_bounds__(1024) void scanA_kernel(
    const int* __restrict__ deg, int* __restrict__ locscan, int* __restrict__ partial)
{
    __shared__ int buf[SCAN_BLK];
    const int t = threadIdx.x;
    const int i = blockIdx.x * SCAN_BLK + t;
    int v = (i < N_NODES) ? deg[i] : 0;
    buf[t] = v;
    __syncthreads();
    #pragma unroll
    for (int off = 1; off < SCAN_BLK; off <<= 1) {
        int xx = (t >= off) ? buf[t - off] : 0;
        __syncthreads();
        buf[t] += xx;
        __syncthreads();
    }
    if (i < N_NODES) locscan[i] = buf[t] - v;           // exclusive
    if (t == SCAN_BLK - 1) partial[blockIdx.x] = buf[t]; // block total
}

// Phase B: one wave scans the 49 block totals -> exclusive prefix
__global__ void scanB_kernel(int* __restrict__ partial)
{
    const int t = threadIdx.x;   // 0..63
    int orig = (t < SCAN_NB) ? partial[t] : 0;
    int v = orig;
    #pragma unroll
    for (int off = 1; off < 64; off <<= 1) {
        int xx = __shfl_up(v, off, 64);
        if (t >= off) v += xx;
    }
    if (t < SCAN_NB) partial[t] = v - orig;              // exclusive
}

// Phase C: combine -> offsets & cursor
__global__ void scanC_kernel(const int* __restrict__ locscan, const int* __restrict__ partial,
                             int* __restrict__ offsets, int* __restrict__ cursor)
{
    int i = blockIdx.x * 256 + threadIdx.x;
    if (i >= N_NODES) return;
    int o = locscan[i] + partial[i >> 10];
    offsets[i] = o;
    cursor[i]  = o;
    if (i == 0) offsets[N_NODES] = E_TOT;
}

__global__ void scatter_kernel(const int* __restrict__ esrc, const int* __restrict__ edst,
                               int* __restrict__ cursor, int* __restrict__ csr_src)
{
    int e = blockIdx.x * blockDim.x + threadIdx.x;
    if (e >= E_TOT) return;
    int s, d;
    if (e < N_EDGES) { s = esrc[e]; d = edst[e]; } else { s = d = e - N_EDGES; }
    int pos = atomicAdd(&cursor[d], 1);
    csr_src[pos] = s;
}

// ---------- layer 1 fused: chunked softmax + aggregate + bias + ELU ----------
__global__ __launch_bounds__(256) void fused_agg1_kernel(
    const int* __restrict__ csr_src, const int* __restrict__ offsets,
    const float* __restrict__ s_src, const float* __restrict__ s_dst,
    const float* __restrict__ h, const float* __restrict__ b,
    float* __restrict__ h2)
{
    const int wid  = threadIdx.x >> 6;
    const int lane = threadIdx.x & 63;
    const int d = blockIdx.x * 4 + wid;
    if (d >= N_NODES) return;
    const int beg = offsets[d], end = offsets[d + 1];
    const float sd0 = s_dst[d * 2], sd1 = s_dst[d * 2 + 1];
    float m0 = -1e30f, m1 = -1e30f;
    float den0 = 0.f, den1 = 0.f, acc0 = 0.f, acc1 = 0.f;

    for (int pos = beg; pos < end; pos += 64) {
        const int n = min(64, end - pos);
        int s = 0;
        float v0 = -1e30f, v1 = -1e30f;
        if (lane < n) {
            s = csr_src[pos + lane];
            const float2 ss = *(const float2*)&s_src[s * 2];
            v0 = ss.x + sd0;  v0 = v0 > 0.f ? v0 : 0.2f * v0;
            v1 = ss.y + sd1;  v1 = v1 > 0.f ? v1 : 0.2f * v1;
        }
        float cm0 = v0, cm1 = v1;
        #pragma unroll
        for (int off = 32; off >= 1; off >>= 1) {
            cm0 = fmaxf(cm0, __shfl_xor(cm0, off, 64));
            cm1 = fmaxf(cm1, __shfl_xor(cm1, off, 64));
        }
        const float nm0 = fmaxf(m0, cm0), nm1 = fmaxf(m1, cm1);
        const float sc0 = __expf(m0 - nm0), sc1 = __expf(m1 - nm1);
        acc0 *= sc0; den0 *= sc0;
        acc1 *= sc1; den1 *= sc1;
        m0 = nm0; m1 = nm1;
        const float e0 = (lane < n) ? __expf(v0 - nm0) : 0.f;
        const float e1 = (lane < n) ? __expf(v1 - nm1) : 0.f;
        float t0 = e0, t1 = e1;
        #pragma unroll
        for (int off = 32; off >= 1; off >>= 1) {
            t0 += __shfl_xor(t0, off, 64);
            t1 += __shfl_xor(t1, off, 64);
        }
        den0 += t0; den1 += t1;
        for (int i = 0; i < n; ++i) {
            const int   si = __builtin_amdgcn_readlane(s, i);
            const float a0 = bcast_f(e0, i);
            const float a1 = bcast_f(e1, i);
            const float* hp = h + (size_t)si * 128;
            acc0 += a0 * hp[lane];
            acc1 += a1 * hp[64 + lane];
        }
    }
    float o0 = acc0 / den0 + b[lane];
    float o1 = acc1 / den1 + b[64 + lane];
    o0 = o0 > 0.f ? o0 : expm1f(o0);
    o1 = o1 > 0.f ? o1 : expm1f(o1);
    h2[d * 128 + lane]      = o0;
    h2[d * 128 + 64 + lane] = o1;
}

// ---------- layer 2 fused: chunked softmax + aggregate + bias -> out ----------
__global__ __launch_bounds__(256) void fused_agg2_kernel(
    const int* __restrict__ csr_src, const int* __restrict__ offsets,
    const float* __restrict__ s_src, const float* __restrict__ s_dst,
    const float* __restrict__ g, const float* __restrict__ b,
    float* __restrict__ out)
{
    const int grp      = threadIdx.x >> 5;
    const int lane     = threadIdx.x & 31;
    const int halfbase = threadIdx.x & 32;
    const int d = blockIdx.x * 8 + grp;
    if (d >= N_NODES) return;
    const int beg = offsets[d], end = offsets[d + 1];
    const float sd = s_dst[d];
    float m = -1e30f, den = 0.f, acc = 0.f;

    for (int pos = beg; pos < end; pos += 32) {
        const int n = min(32, end - pos);
        int s = 0;
        float v = -1e30f;
        if (lane < n) {
            s = csr_src[pos + lane];
            v = s_src[s] + sd;  v = v > 0.f ? v : 0.2f * v;
        }
        float cm = v;
        #pragma unroll
        for (int off = 16; off >= 1; off >>= 1)
            cm = fmaxf(cm, __shfl_xor(cm, off, 32));
        const float nm = fmaxf(m, cm);
        const float sc = __expf(m - nm);
        acc *= sc; den *= sc;
        m = nm;
        const float e = (lane < n) ? __expf(v - nm) : 0.f;
        float t = e;
        #pragma unroll
        for (int off = 16; off >= 1; off >>= 1)
            t += __shfl_xor(t, off, 32);
        den += t;
        for (int i = 0; i < n; ++i) {
            const int   si = __shfl(s, i + halfbase, 64);   // bpermute: per-lane src ok
            const float a  = __shfl(e, i + halfbase, 64);
            acc += a * g[(size_t)si * 32 + lane];
        }
    }
    out[d * 32 + lane] = acc / den + b[lane];
}

extern "C" void kernel_launch(void* const* d_in, const int* in_sizes, int n_in,
                              void* d_out, int out_size, void* d_ws, size_t ws_size,
                              hipStream_t stream)
{
    const float* x   = (const float*)d_in[0];
    const int*   ei  = (const int*)d_in[1];     // [2, E] int32: row0 = src, row1 = dst
    const float* W1  = (const float*)d_in[2];
    const float* a1s = (const float*)d_in[3];
    const float* a1d = (const float*)d_in[4];
    const float* b1  = (const float*)d_in[5];
    const float* W2  = (const float*)d_in[6];
    const float* a2s = (const float*)d_in[7];
    const float* a2d = (const float*)d_in[8];
    const float* b2  = (const float*)d_in[9];
    float* out = (float*)d_out;

    const int* esrc = ei;
    const int* edst = ei + N_EDGES;

    // -------- workspace layout --------
    float* ws = (float*)d_ws;
    float* h1  = ws;                                 // N*128
    float* h2  = h1  + (size_t)N_NODES * 128;        // N*128
    float* s1s = h2  + (size_t)N_NODES * 128;        // 2N
    float* s1d = s1s + 2 * N_NODES;                  // 2N
    float* s2s = s1d + 2 * N_NODES;                  // N
    float* s2d = s2s + N_NODES;                      // N
    int* deg     = (int*)(s2d + N_NODES);            // N
    int* offsets = deg + N_NODES;                    // N+1
    int* cursor  = offsets + N_NODES + 1;            // N
    int* csr_src = cursor + N_NODES;                 // E_TOT
    int* locscan = csr_src + E_TOT;                  // N
    int* partial = locscan + N_NODES;                // 64
    float* g2 = h1;                                  // N*32 (h1 dead after fused_agg1)

    // -------- CSR build --------
    hipMemsetAsync(deg, 0, (size_t)N_NODES * 4, stream);
    hist_kernel<<<(E_TOT + 255) / 256, 256, 0, stream>>>(edst, deg);
    scanA_kernel<<<SCAN_NB, SCAN_BLK, 0, stream>>>(deg, locscan, partial);
    scanB_kernel<<<1, 64, 0, stream>>>(partial);
    scanC_kernel<<<(N_NODES + 255) / 256, 256, 0, stream>>>(locscan, partial, offsets, cursor);
    scatter_kernel<<<(E_TOT + 255) / 256, 256, 0, stream>>>(esrc, edst, cursor, csr_src);

    // -------- layer 1 --------
    gemm1_tiled<<<((N_NODES + 63) / 64) * 2, 128, 0, stream>>>(x, W1, a1s, a1d, h1, s1s, s1d);
    fused_agg1_kernel<<<(N_NODES + 3) / 4, 256, 0, stream>>>(
        csr_src, offsets, s1s, s1d, h1, b1, h2);

    // -------- layer 2 --------
    gemm2_tiled<<<(N_NODES + 127) / 128, 128, 0, stream>>>(h2, W2, a2s, a2d, g2, s2s, s2d);
    fused_agg2_kernel<<<(N_NODES + 7) / 8, 256, 0, stream>>>(
        csr_src, offsets, s2s, s2d, g2, b2, out);
}

// Round 7
// 264.403 us; speedup vs baseline: 2.8994x; 1.1076x over previous
//
#include <hip/hip_runtime.h>
#include <math.h>

#define N_NODES 50000
#define N_EDGES 800000
#define E_TOT   (N_EDGES + N_NODES)   // 850000 edges incl. self loops
#define SCAN_BLK 1024
#define SCAN_NB  ((N_NODES + SCAN_BLK - 1) / SCAN_BLK)   // 49

__device__ __forceinline__ float bcast_f(float v, int srclane) {
    return __uint_as_float(__builtin_amdgcn_readlane(__float_as_uint(v), srclane));
}

// ================= layer 1 GEMM: h1 = x @ W1  [N,128]x[128,128] ================
__global__ __launch_bounds__(128) void gemm1_tiled(
    const float* __restrict__ x, const float* __restrict__ W,
    const float* __restrict__ a_src, const float* __restrict__ a_dst,
    float* __restrict__ h, float* __restrict__ s_src, float* __restrict__ s_dst)
{
    __shared__ float xs[64][68];
    __shared__ float wt[64][68];
    const int tid  = threadIdx.x;
    const int colT = tid & 15;
    const int rowT = tid >> 4;
    const int half = blockIdx.x & 1;          // head
    const int r0   = (blockIdx.x >> 1) * 64;
    const int c0   = half * 64;

    float acc[4][8];
    #pragma unroll
    for (int j = 0; j < 4; ++j)
        #pragma unroll
        for (int i = 0; i < 8; ++i) acc[j][i] = 0.f;

    for (int kc = 0; kc < 2; ++kc) {
        const int kbase = kc * 64;
        #pragma unroll
        for (int it = 0; it < 8; ++it) {
            int q = it * 128 + tid;
            int row = q >> 4, k4 = q & 15;
            float4 v = make_float4(0.f, 0.f, 0.f, 0.f);
            if (r0 + row < N_NODES)
                v = *(const float4*)&x[(size_t)(r0 + row) * 128 + kbase + k4 * 4];
            *(float4*)&xs[row][k4 * 4] = v;
        }
        #pragma unroll
        for (int it = 0; it < 8; ++it) {
            int q = it * 128 + tid;
            int c = q & 63, k4 = q >> 6;
            float4 v;
            v.x = W[(kbase + k4 * 4 + 0) * 128 + c0 + c];
            v.y = W[(kbase + k4 * 4 + 1) * 128 + c0 + c];
            v.z = W[(kbase + k4 * 4 + 2) * 128 + c0 + c];
            v.w = W[(kbase + k4 * 4 + 3) * 128 + c0 + c];
            *(float4*)&wt[c][k4 * 4] = v;
        }
        __syncthreads();
        #pragma unroll 4
        for (int k4 = 0; k4 < 16; ++k4) {
            float4 wv[4], xv[8];
            #pragma unroll
            for (int j = 0; j < 4; ++j) wv[j] = *(const float4*)&wt[colT + 16 * j][k4 * 4];
            #pragma unroll
            for (int i = 0; i < 8; ++i) xv[i] = *(const float4*)&xs[rowT + 8 * i][k4 * 4];
            #pragma unroll
            for (int j = 0; j < 4; ++j)
                #pragma unroll
                for (int i = 0; i < 8; ++i)
                    acc[j][i] += wv[j].x * xv[i].x + wv[j].y * xv[i].y
                               + wv[j].z * xv[i].z + wv[j].w * xv[i].w;
        }
        __syncthreads();
    }

    #pragma unroll
    for (int i = 0; i < 8; ++i) {
        const int row = r0 + rowT + 8 * i;
        float vs = 0.f, vd = 0.f;
        #pragma unroll
        for (int j = 0; j < 4; ++j) {
            const int c = c0 + colT + 16 * j;
            const float a = acc[j][i];
            vs += a * a_src[c];
            vd += a * a_dst[c];
            if (row < N_NODES) h[(size_t)row * 128 + c] = a;
        }
        #pragma unroll
        for (int off = 8; off >= 1; off >>= 1) {
            vs += __shfl_xor(vs, off, 64);
            vd += __shfl_xor(vd, off, 64);
        }
        if (colT == 0 && row < N_NODES) {
            s_src[row * 2 + half] = vs;
            s_dst[row * 2 + half] = vd;
        }
    }
}

// ================= layer 2 GEMM: g = h2 @ W2  [N,128]x[128,32] ================
__global__ __launch_bounds__(128) void gemm2_tiled(
    const float* __restrict__ h2, const float* __restrict__ W,
    const float* __restrict__ a_src, const float* __restrict__ a_dst,
    float* __restrict__ g, float* __restrict__ s_src, float* __restrict__ s_dst)
{
    __shared__ float xs[128][68];
    __shared__ float wt[32][68];
    const int tid  = threadIdx.x;
    const int colT = tid & 7;
    const int rowT = tid >> 3;
    const int r0   = blockIdx.x * 128;

    float acc[4][8];
    #pragma unroll
    for (int j = 0; j < 4; ++j)
        #pragma unroll
        for (int i = 0; i < 8; ++i) acc[j][i] = 0.f;

    for (int kc = 0; kc < 2; ++kc) {
        const int kbase = kc * 64;
        #pragma unroll
        for (int it = 0; it < 16; ++it) {
            int q = it * 128 + tid;
            int row = q >> 4, k4 = q & 15;
            float4 v = make_float4(0.f, 0.f, 0.f, 0.f);
            if (r0 + row < N_NODES)
                v = *(const float4*)&h2[(size_t)(r0 + row) * 128 + kbase + k4 * 4];
            *(float4*)&xs[row][k4 * 4] = v;
        }
        #pragma unroll
        for (int it = 0; it < 4; ++it) {
            int q = it * 128 + tid;
            int c = q & 31, k4 = q >> 5;
            float4 v;
            v.x = W[(kbase + k4 * 4 + 0) * 32 + c];
            v.y = W[(kbase + k4 * 4 + 1) * 32 + c];
            v.z = W[(kbase + k4 * 4 + 2) * 32 + c];
            v.w = W[(kbase + k4 * 4 + 3) * 32 + c];
            *(float4*)&wt[c][k4 * 4] = v;
        }
        __syncthreads();
        #pragma unroll 4
        for (int k4 = 0; k4 < 16; ++k4) {
            float4 wv[4], xv[8];
            #pragma unroll
            for (int j = 0; j < 4; ++j) wv[j] = *(const float4*)&wt[colT + 8 * j][k4 * 4];
            #pragma unroll
            for (int i = 0; i < 8; ++i) xv[i] = *(const float4*)&xs[rowT + 16 * i][k4 * 4];
            #pragma unroll
            for (int j = 0; j < 4; ++j)
                #pragma unroll
                for (int i = 0; i < 8; ++i)
                    acc[j][i] += wv[j].x * xv[i].x + wv[j].y * xv[i].y
                               + wv[j].z * xv[i].z + wv[j].w * xv[i].w;
        }
        __syncthreads();
    }

    #pragma unroll
    for (int i = 0; i < 8; ++i) {
        const int row = r0 + rowT + 16 * i;
        float vs = 0.f, vd = 0.f;
        #pragma unroll
        for (int j = 0; j < 4; ++j) {
            const int c = colT + 8 * j;
            const float a = acc[j][i];
            vs += a * a_src[c];
            vd += a * a_dst[c];
            if (row < N_NODES) g[(size_t)row * 32 + c] = a;
        }
        #pragma unroll
        for (int off = 4; off >= 1; off >>= 1) {
            vs += __shfl_xor(vs, off, 64);
            vd += __shfl_xor(vd, off, 64);
        }
        if (colT == 0 && row < N_NODES) {
            s_src[row] = vs;
            s_dst[row] = vd;
        }
    }
}

// ---------- CSR build ----------
__global__ void hist_kernel(const int* __restrict__ edst, int* __restrict__ deg)
{
    int e = blockIdx.x * blockDim.x + threadIdx.x;
    if (e >= E_TOT) return;
    int d = (e < N_EDGES) ? edst[e] : (e - N_EDGES);
    atomicAdd(&deg[d], 1);
}

__global__ __launch_bounds__(1024) void scanA_kernel(
    const int* __restrict__ deg, int* __restrict__ locscan, int* __restrict__ partial)
{
    __shared__ int buf[SCAN_BLK];
    const int t = threadIdx.x;
    const int i = blockIdx.x * SCAN_BLK + t;
    int v = (i < N_NODES) ? deg[i] : 0;
    buf[t] = v;
    __syncthreads();
    #pragma unroll
    for (int off = 1; off < SCAN_BLK; off <<= 1) {
        int xx = (t >= off) ? buf[t - off] : 0;
        __syncthreads();
        buf[t] += xx;
        __syncthreads();
    }
    if (i < N_NODES) locscan[i] = buf[t] - v;
    if (t == SCAN_BLK - 1) partial[blockIdx.x] = buf[t];
}

__global__ void scanB_kernel(int* __restrict__ partial)
{
    const int t = threadIdx.x;   // 0..63
    int orig = (t < SCAN_NB) ? partial[t] : 0;
    int v = orig;
    #pragma unroll
    for (int off = 1; off < 64; off <<= 1) {
        int xx = __shfl_up(v, off, 64);
        if (t >= off) v += xx;
    }
    if (t < SCAN_NB) partial[t] = v - orig;
}

__global__ void scanC_kernel(const int* __restrict__ locscan, const int* __restrict__ partial,
                             int* __restrict__ offsets, int* __restrict__ cursor)
{
    int i = blockIdx.x * 256 + threadIdx.x;
    if (i >= N_NODES) return;
    int o = locscan[i] + partial[i >> 10];
    offsets[i] = o;
    cursor[i]  = o;
    if (i == 0) offsets[N_NODES] = E_TOT;
}

__global__ void scatter_kernel(const int* __restrict__ esrc, const int* __restrict__ edst,
                               int* __restrict__ cursor, int* __restrict__ csr_src)
{
    int e = blockIdx.x * blockDim.x + threadIdx.x;
    if (e >= E_TOT) return;
    int s, d;
    if (e < N_EDGES) { s = esrc[e]; d = edst[e]; } else { s = d = e - N_EDGES; }
    int pos = atomicAdd(&cursor[d], 1);
    csr_src[pos] = s;
}

// ---------- layer 1 fused: chunked softmax + float4 pipelined gather ----------
// one wave per node. Lane q=lane&31 owns channels 4q..4q+3 (q<16 -> head0).
// The two 32-lane halves process 2 edges per iteration (one dwordx4 load each).
__global__ __launch_bounds__(256) void fused_agg1_kernel(
    const int* __restrict__ csr_src, const int* __restrict__ offsets,
    const float* __restrict__ s_src, const float* __restrict__ s_dst,
    const float* __restrict__ h, const float* __restrict__ b,
    float* __restrict__ h2)
{
    const int wid  = threadIdx.x >> 6;
    const int lane = threadIdx.x & 63;
    const int q    = lane & 31;
    const bool odd    = lane >= 32;       // this half processes odd edge slots
    const bool headhi = q >= 16;          // channels 64..127
    const int d = blockIdx.x * 4 + wid;
    if (d >= N_NODES) return;
    const int beg = offsets[d], end = offsets[d + 1];
    const float sd0 = s_dst[d * 2], sd1 = s_dst[d * 2 + 1];
    float m0 = -1e30f, m1 = -1e30f;
    float den0 = 0.f, den1 = 0.f;
    float4 acc = make_float4(0.f, 0.f, 0.f, 0.f);

    for (int pos = beg; pos < end; pos += 64) {
        const int n = min(64, end - pos);
        int s = 0;
        float v0 = -1e30f, v1 = -1e30f;
        if (lane < n) {
            s = csr_src[pos + lane];
            const float2 ss = *(const float2*)&s_src[s * 2];
            v0 = ss.x + sd0;  v0 = v0 > 0.f ? v0 : 0.2f * v0;
            v1 = ss.y + sd1;  v1 = v1 > 0.f ? v1 : 0.2f * v1;
        }
        float cm0 = v0, cm1 = v1;
        #pragma unroll
        for (int off = 32; off >= 1; off >>= 1) {
            cm0 = fmaxf(cm0, __shfl_xor(cm0, off, 64));
            cm1 = fmaxf(cm1, __shfl_xor(cm1, off, 64));
        }
        const float nm0 = fmaxf(m0, cm0), nm1 = fmaxf(m1, cm1);
        const float sc0 = __expf(m0 - nm0), sc1 = __expf(m1 - nm1);
        den0 *= sc0; den1 *= sc1;
        const float asc = headhi ? sc1 : sc0;
        acc.x *= asc; acc.y *= asc; acc.z *= asc; acc.w *= asc;
        m0 = nm0; m1 = nm1;
        const float e0 = (lane < n) ? __expf(v0 - nm0) : 0.f;
        const float e1 = (lane < n) ? __expf(v1 - nm1) : 0.f;
        float t0 = e0, t1 = e1;
        #pragma unroll
        for (int off = 32; off >= 1; off >>= 1) {
            t0 += __shfl_xor(t0, off, 64);
            t1 += __shfl_xor(t1, off, 64);
        }
        den0 += t0; den1 += t1;

        // pipelined float4 gather: 2 edges per iteration
        const int steps = (n + 1) >> 1;
        int sia = __builtin_amdgcn_readlane(s, 0);
        int sib = __builtin_amdgcn_readlane(s, 1);
        int si  = odd ? sib : sia;
        float4 hv = *(const float4*)&h[(size_t)si * 128 + q * 4];
        for (int i = 0; i < steps; ++i) {
            const float e0a = bcast_f(e0, 2 * i),     e1a = bcast_f(e1, 2 * i);
            const float e0b = bcast_f(e0, 2 * i + 1), e1b = bcast_f(e1, 2 * i + 1);
            const float a = headhi ? (odd ? e1b : e1a) : (odd ? e0b : e0a);
            const float4 cur = hv;
            if (i + 1 < steps) {
                const int na = __builtin_amdgcn_readlane(s, 2 * i + 2);
                const int nb = __builtin_amdgcn_readlane(s, 2 * i + 3);
                si = odd ? nb : na;
                hv = *(const float4*)&h[(size_t)si * 128 + q * 4];
            }
            acc.x += a * cur.x;
            acc.y += a * cur.y;
            acc.z += a * cur.z;
            acc.w += a * cur.w;
        }
    }
    // combine the two edge-parity halves
    acc.x += __shfl_xor(acc.x, 32, 64);
    acc.y += __shfl_xor(acc.y, 32, 64);
    acc.z += __shfl_xor(acc.z, 32, 64);
    acc.w += __shfl_xor(acc.w, 32, 64);
    if (lane < 32) {
        const float den = headhi ? den1 : den0;
        const float4 b4 = *(const float4*)&b[q * 4];
        float4 o;
        o.x = acc.x / den + b4.x;
        o.y = acc.y / den + b4.y;
        o.z = acc.z / den + b4.z;
        o.w = acc.w / den + b4.w;
        o.x = o.x > 0.f ? o.x : expm1f(o.x);
        o.y = o.y > 0.f ? o.y : expm1f(o.y);
        o.z = o.z > 0.f ? o.z : expm1f(o.z);
        o.w = o.w > 0.f ? o.w : expm1f(o.w);
        *(float4*)&h2[(size_t)d * 128 + q * 4] = o;
    }
}

// ---------- layer 2 fused: chunked softmax + float4 pipelined gather ----------
// one 32-lane group per node; 4 edges per iteration (8 lanes each, float4).
// Broadcasts use __shfl (bpermute) since groups are not wave-uniform.
__global__ __launch_bounds__(256) void fused_agg2_kernel(
    const int* __restrict__ csr_src, const int* __restrict__ offsets,
    const float* __restrict__ s_src, const float* __restrict__ s_dst,
    const float* __restrict__ g, const float* __restrict__ b,
    float* __restrict__ out)
{
    const int grp      = threadIdx.x >> 5;
    const int q        = threadIdx.x & 31;
    const int halfbase = threadIdx.x & 32;
    const int slot     = q >> 3;       // edge slot 0..3
    const int r        = q & 7;        // channel quad: channels 4r..4r+3
    const int d = blockIdx.x * 8 + grp;
    if (d >= N_NODES) return;
    const int beg = offsets[d], end = offsets[d + 1];
    const float sd = s_dst[d];
    float m = -1e30f, den = 0.f;
    float4 acc = make_float4(0.f, 0.f, 0.f, 0.f);

    for (int pos = beg; pos < end; pos += 32) {
        const int n = min(32, end - pos);
        int s = 0;
        float v = -1e30f;
        if (q < n) {
            s = csr_src[pos + q];
            v = s_src[s] + sd;  v = v > 0.f ? v : 0.2f * v;
        }
        float cm = v;
        #pragma unroll
        for (int off = 16; off >= 1; off >>= 1)
            cm = fmaxf(cm, __shfl_xor(cm, off, 32));
        const float nm = fmaxf(m, cm);
        const float sc = __expf(m - nm);
        den *= sc;
        acc.x *= sc; acc.y *= sc; acc.z *= sc; acc.w *= sc;
        m = nm;
        const float e = (q < n) ? __expf(v - nm) : 0.f;
        float t = e;
        #pragma unroll
        for (int off = 16; off >= 1; off >>= 1)
            t += __shfl_xor(t, off, 32);
        den += t;

        const int steps = (n + 3) >> 2;
        int src0 = halfbase + min(slot, 31);
        int si = __shfl(s, src0, 64);
        float4 gv = *(const float4*)&g[(size_t)si * 32 + r * 4];
        for (int i = 0; i < steps; ++i) {
            const float a = __shfl(e, halfbase + min(4 * i + slot, 31), 64);
            const float4 cur = gv;
            const int jn = halfbase + min(4 * (i + 1) + slot, 31);
            si = __shfl(s, jn, 64);
            gv = *(const float4*)&g[(size_t)si * 32 + r * 4];
            acc.x += a * cur.x;
            acc.y += a * cur.y;
            acc.z += a * cur.z;
            acc.w += a * cur.w;
        }
    }
    // combine the 4 edge slots (within the 32-lane group)
    acc.x += __shfl_xor(acc.x, 8, 32);  acc.y += __shfl_xor(acc.y, 8, 32);
    acc.z += __shfl_xor(acc.z, 8, 32);  acc.w += __shfl_xor(acc.w, 8, 32);
    acc.x += __shfl_xor(acc.x, 16, 32); acc.y += __shfl_xor(acc.y, 16, 32);
    acc.z += __shfl_xor(acc.z, 16, 32); acc.w += __shfl_xor(acc.w, 16, 32);
    if (slot == 0) {
        const float4 b4 = *(const float4*)&b[r * 4];
        float4 o;
        o.x = acc.x / den + b4.x;
        o.y = acc.y / den + b4.y;
        o.z = acc.z / den + b4.z;
        o.w = acc.w / den + b4.w;
        *(float4*)&out[(size_t)d * 32 + r * 4] = o;
    }
}

extern "C" void kernel_launch(void* const* d_in, const int* in_sizes, int n_in,
                              void* d_out, int out_size, void* d_ws, size_t ws_size,
                              hipStream_t stream)
{
    const float* x   = (const float*)d_in[0];
    const int*   ei  = (const int*)d_in[1];     // [2, E] int32: row0 = src, row1 = dst
    const float* W1  = (const float*)d_in[2];
    const float* a1s = (const float*)d_in[3];
    const float* a1d = (const float*)d_in[4];
    const float* b1  = (const float*)d_in[5];
    const float* W2  = (const float*)d_in[6];
    const float* a2s = (const float*)d_in[7];
    const float* a2d = (const float*)d_in[8];
    const float* b2  = (const float*)d_in[9];
    float* out = (float*)d_out;

    const int* esrc = ei;
    const int* edst = ei + N_EDGES;

    // -------- workspace layout --------
    float* ws = (float*)d_ws;
    float* h1  = ws;                                 // N*128
    float* h2  = h1  + (size_t)N_NODES * 128;        // N*128
    float* s1s = h2  + (size_t)N_NODES * 128;        // 2N
    float* s1d = s1s + 2 * N_NODES;                  // 2N
    float* s2s = s1d + 2 * N_NODES;                  // N
    float* s2d = s2s + N_NODES;                      // N
    int* deg     = (int*)(s2d + N_NODES);            // N
    int* offsets = deg + N_NODES;                    // N+1
    int* cursor  = offsets + N_NODES + 1;            // N
    int* csr_src = cursor + N_NODES;                 // E_TOT
    int* locscan = csr_src + E_TOT;                  // N
    int* partial = locscan + N_NODES;                // 64
    float* g2 = h1;                                  // N*32 (h1 dead after fused_agg1)

    // -------- CSR build --------
    hipMemsetAsync(deg, 0, (size_t)N_NODES * 4, stream);
    hist_kernel<<<(E_TOT + 255) / 256, 256, 0, stream>>>(edst, deg);
    scanA_kernel<<<SCAN_NB, SCAN_BLK, 0, stream>>>(deg, locscan, partial);
    scanB_kernel<<<1, 64, 0, stream>>>(partial);
    scanC_kernel<<<(N_NODES + 255) / 256, 256, 0, stream>>>(locscan, partial, offsets, cursor);
    scatter_kernel<<<(E_TOT + 255) / 256, 256, 0, stream>>>(esrc, edst, cursor, csr_src);

    // -------- layer 1 --------
    gemm1_tiled<<<((N_NODES + 63) / 64) * 2, 128, 0, stream>>>(x, W1, a1s, a1d, h1, s1s, s1d);
    fused_agg1_kernel<<<(N_NODES + 3) / 4, 256, 0, stream>>>(
        csr_src, offsets, s1s, s1d, h1, b1, h2);

    // -------- layer 2 --------
    gemm2_tiled<<<(N_NODES + 127) / 128, 128, 0, stream>>>(h2, W2, a2s, a2d, g2, s2s, s2d);
    fused_agg2_kernel<<<(N_NODES + 7) / 8, 256, 0, stream>>>(
        csr_src, offsets, s2s, s2d, g2, b2, out);
}

// Round 9
// 249.863 us; speedup vs baseline: 3.0681x; 1.0582x over previous
//
#include <hip/hip_runtime.h>
#include <hip/hip_fp16.h>
#include <math.h>

#define N_NODES 50000
#define N_EDGES 800000
#define E_TOT   (N_EDGES + N_NODES)   // 850000 edges incl. self loops
#define SCAN_BLK 1024
#define SCAN_NB  ((N_NODES + SCAN_BLK - 1) / SCAN_BLK)   // 49

// ================= layer 1 GEMM: h1 = x @ W1  [N,128]x[128,128] ================
// h stored as fp16 (gather target); scores computed from fp32 accumulators
__global__ __launch_bounds__(128) void gemm1_tiled(
    const float* __restrict__ x, const float* __restrict__ W,
    const float* __restrict__ a_src, const float* __restrict__ a_dst,
    __half* __restrict__ h, float* __restrict__ s_src, float* __restrict__ s_dst)
{
    __shared__ float xs[64][68];
    __shared__ float wt[64][68];
    const int tid  = threadIdx.x;
    const int colT = tid & 15;
    const int rowT = tid >> 4;
    const int half = blockIdx.x & 1;          // head
    const int r0   = (blockIdx.x >> 1) * 64;
    const int c0   = half * 64;

    float acc[4][8];
    #pragma unroll
    for (int j = 0; j < 4; ++j)
        #pragma unroll
        for (int i = 0; i < 8; ++i) acc[j][i] = 0.f;

    for (int kc = 0; kc < 2; ++kc) {
        const int kbase = kc * 64;
        #pragma unroll
        for (int it = 0; it < 8; ++it) {
            int q = it * 128 + tid;
            int row = q >> 4, k4 = q & 15;
            float4 v = make_float4(0.f, 0.f, 0.f, 0.f);
            if (r0 + row < N_NODES)
                v = *(const float4*)&x[(size_t)(r0 + row) * 128 + kbase + k4 * 4];
            *(float4*)&xs[row][k4 * 4] = v;
        }
        #pragma unroll
        for (int it = 0; it < 8; ++it) {
            int q = it * 128 + tid;
            int c = q & 63, k4 = q >> 6;
            float4 v;
            v.x = W[(kbase + k4 * 4 + 0) * 128 + c0 + c];
            v.y = W[(kbase + k4 * 4 + 1) * 128 + c0 + c];
            v.z = W[(kbase + k4 * 4 + 2) * 128 + c0 + c];
            v.w = W[(kbase + k4 * 4 + 3) * 128 + c0 + c];
            *(float4*)&wt[c][k4 * 4] = v;
        }
        __syncthreads();
        #pragma unroll 4
        for (int k4 = 0; k4 < 16; ++k4) {
            float4 wv[4], xv[8];
            #pragma unroll
            for (int j = 0; j < 4; ++j) wv[j] = *(const float4*)&wt[colT + 16 * j][k4 * 4];
            #pragma unroll
            for (int i = 0; i < 8; ++i) xv[i] = *(const float4*)&xs[rowT + 8 * i][k4 * 4];
            #pragma unroll
            for (int j = 0; j < 4; ++j)
                #pragma unroll
                for (int i = 0; i < 8; ++i)
                    acc[j][i] += wv[j].x * xv[i].x + wv[j].y * xv[i].y
                               + wv[j].z * xv[i].z + wv[j].w * xv[i].w;
        }
        __syncthreads();
    }

    #pragma unroll
    for (int i = 0; i < 8; ++i) {
        const int row = r0 + rowT + 8 * i;
        float vs = 0.f, vd = 0.f;
        #pragma unroll
        for (int j = 0; j < 4; ++j) {
            const int c = c0 + colT + 16 * j;
            const float a = acc[j][i];
            vs += a * a_src[c];
            vd += a * a_dst[c];
            if (row < N_NODES) h[(size_t)row * 128 + c] = __float2half(a);
        }
        #pragma unroll
        for (int off = 8; off >= 1; off >>= 1) {
            vs += __shfl_xor(vs, off, 64);
            vd += __shfl_xor(vd, off, 64);
        }
        if (colT == 0 && row < N_NODES) {
            s_src[row * 2 + half] = vs;
            s_dst[row * 2 + half] = vd;
        }
    }
}

// ================= layer 2 GEMM: g = h2 @ W2  [N,128]x[128,32] ================
__global__ __launch_bounds__(128) void gemm2_tiled(
    const float* __restrict__ h2, const float* __restrict__ W,
    const float* __restrict__ a_src, const float* __restrict__ a_dst,
    __half* __restrict__ g, float* __restrict__ s_src, float* __restrict__ s_dst)
{
    __shared__ float xs[128][68];
    __shared__ float wt[32][68];
    const int tid  = threadIdx.x;
    const int colT = tid & 7;
    const int rowT = tid >> 3;
    const int r0   = blockIdx.x * 128;

    float acc[4][8];
    #pragma unroll
    for (int j = 0; j < 4; ++j)
        #pragma unroll
        for (int i = 0; i < 8; ++i) acc[j][i] = 0.f;

    for (int kc = 0; kc < 2; ++kc) {
        const int kbase = kc * 64;
        #pragma unroll
        for (int it = 0; it < 16; ++it) {
            int q = it * 128 + tid;
            int row = q >> 4, k4 = q & 15;
            float4 v = make_float4(0.f, 0.f, 0.f, 0.f);
            if (r0 + row < N_NODES)
                v = *(const float4*)&h2[(size_t)(r0 + row) * 128 + kbase + k4 * 4];
            *(float4*)&xs[row][k4 * 4] = v;
        }
        #pragma unroll
        for (int it = 0; it < 4; ++it) {
            int q = it * 128 + tid;
            int c = q & 31, k4 = q >> 5;
            float4 v;
            v.x = W[(kbase + k4 * 4 + 0) * 32 + c];
            v.y = W[(kbase + k4 * 4 + 1) * 32 + c];
            v.z = W[(kbase + k4 * 4 + 2) * 32 + c];
            v.w = W[(kbase + k4 * 4 + 3) * 32 + c];
            *(float4*)&wt[c][k4 * 4] = v;
        }
        __syncthreads();
        #pragma unroll 4
        for (int k4 = 0; k4 < 16; ++k4) {
            float4 wv[4], xv[8];
            #pragma unroll
            for (int j = 0; j < 4; ++j) wv[j] = *(const float4*)&wt[colT + 8 * j][k4 * 4];
            #pragma unroll
            for (int i = 0; i < 8; ++i) xv[i] = *(const float4*)&xs[rowT + 16 * i][k4 * 4];
            #pragma unroll
            for (int j = 0; j < 4; ++j)
                #pragma unroll
                for (int i = 0; i < 8; ++i)
                    acc[j][i] += wv[j].x * xv[i].x + wv[j].y * xv[i].y
                               + wv[j].z * xv[i].z + wv[j].w * xv[i].w;
        }
        __syncthreads();
    }

    #pragma unroll
    for (int i = 0; i < 8; ++i) {
        const int row = r0 + rowT + 16 * i;
        float vs = 0.f, vd = 0.f;
        #pragma unroll
        for (int j = 0; j < 4; ++j) {
            const int c = colT + 8 * j;
            const float a = acc[j][i];
            vs += a * a_src[c];
            vd += a * a_dst[c];
            if (row < N_NODES) g[(size_t)row * 32 + c] = __float2half(a);
        }
        #pragma unroll
        for (int off = 4; off >= 1; off >>= 1) {
            vs += __shfl_xor(vs, off, 64);
            vd += __shfl_xor(vd, off, 64);
        }
        if (colT == 0 && row < N_NODES) {
            s_src[row] = vs;
            s_dst[row] = vd;
        }
    }
}

// ---------- CSR build ----------
__global__ void hist_kernel(const int* __restrict__ edst, int* __restrict__ deg)
{
    int e = blockIdx.x * blockDim.x + threadIdx.x;
    if (e >= E_TOT) return;
    int d = (e < N_EDGES) ? edst[e] : (e - N_EDGES);
    atomicAdd(&deg[d], 1);
}

__global__ __launch_bounds__(1024) void scanA_kernel(
    const int* __restrict__ deg, int* __restrict__ locscan, int* __restrict__ partial)
{
    __shared__ int buf[SCAN_BLK];
    const int t = threadIdx.x;
    const int i = blockIdx.x * SCAN_BLK + t;
    int v = (i < N_NODES) ? deg[i] : 0;
    buf[t] = v;
    __syncthreads();
    #pragma unroll
    for (int off = 1; off < SCAN_BLK; off <<= 1) {
        int xx = (t >= off) ? buf[t - off] : 0;
        __syncthreads();
        buf[t] += xx;
        __syncthreads();
    }
    if (i < N_NODES) locscan[i] = buf[t] - v;
    if (t == SCAN_BLK - 1) partial[blockIdx.x] = buf[t];
}

__global__ void scanB_kernel(int* __restrict__ partial)
{
    const int t = threadIdx.x;   // 0..63
    int orig = (t < SCAN_NB) ? partial[t] : 0;
    int v = orig;
    #pragma unroll
    for (int off = 1; off < 64; off <<= 1) {
        int xx = __shfl_up(v, off, 64);
        if (t >= off) v += xx;
    }
    if (t < SCAN_NB) partial[t] = v - orig;
}

__global__ void scanC_kernel(const int* __restrict__ locscan, const int* __restrict__ partial,
                             int* __restrict__ offsets, int* __restrict__ cursor)
{
    int i = blockIdx.x * 256 + threadIdx.x;
    if (i >= N_NODES) return;
    int o = locscan[i] + partial[i >> 10];
    offsets[i] = o;
    cursor[i]  = o;
    if (i == 0) offsets[N_NODES] = E_TOT;
}

__global__ void scatter_kernel(const int* __restrict__ esrc, const int* __restrict__ edst,
                               int* __restrict__ cursor, int* __restrict__ csr_src)
{
    int e = blockIdx.x * blockDim.x + threadIdx.x;
    if (e >= E_TOT) return;
    int s, d;
    if (e < N_EDGES) { s = esrc[e]; d = edst[e]; } else { s = d = e - N_EDGES; }
    int pos = atomicAdd(&cursor[d], 1);
    csr_src[pos] = s;
}

// ---------- layer 1 fused: chunked softmax + fp16 gather (4 edges/iter) ----------
// one wave per node. lane: p = lane&15 -> channels 8p..8p+7; slot = lane>>4 -> edge slot
// NOTE: all __shfl (ds_bpermute) calls are UNCONDITIONAL, full-exec — never inside
// a lane-divergent branch/ternary (convergent-op hazard, see round-4/round-7 bugs).
__global__ __launch_bounds__(256) void fused_agg1_kernel(
    const int* __restrict__ csr_src, const int* __restrict__ offsets,
    const float* __restrict__ s_src, const float* __restrict__ s_dst,
    const __half* __restrict__ h, const float* __restrict__ b,
    float* __restrict__ h2)
{
    const int wid  = threadIdx.x >> 6;
    const int lane = threadIdx.x & 63;
    const int p    = lane & 15;
    const int slot = lane >> 4;
    const bool headhi = p >= 8;           // channels 64..127
    const int d = blockIdx.x * 4 + wid;
    if (d >= N_NODES) return;
    const int beg = offsets[d], end = offsets[d + 1];
    const float sd0 = s_dst[d * 2], sd1 = s_dst[d * 2 + 1];
    float m0 = -1e30f, m1 = -1e30f;
    float den0 = 0.f, den1 = 0.f;
    float acc[8];
    #pragma unroll
    for (int k = 0; k < 8; ++k) acc[k] = 0.f;

    for (int pos = beg; pos < end; pos += 64) {
        const int n = min(64, end - pos);
        int s = 0;
        float v0 = -1e30f, v1 = -1e30f;
        if (lane < n) {
            s = csr_src[pos + lane];
            const float2 ss = *(const float2*)&s_src[s * 2];
            v0 = ss.x + sd0;  v0 = v0 > 0.f ? v0 : 0.2f * v0;
            v1 = ss.y + sd1;  v1 = v1 > 0.f ? v1 : 0.2f * v1;
        }
        float cm0 = v0, cm1 = v1;
        #pragma unroll
        for (int off = 32; off >= 1; off >>= 1) {
            cm0 = fmaxf(cm0, __shfl_xor(cm0, off, 64));
            cm1 = fmaxf(cm1, __shfl_xor(cm1, off, 64));
        }
        const float nm0 = fmaxf(m0, cm0), nm1 = fmaxf(m1, cm1);
        const float sc0 = __expf(m0 - nm0), sc1 = __expf(m1 - nm1);
        den0 *= sc0; den1 *= sc1;
        const float asc = headhi ? sc1 : sc0;
        #pragma unroll
        for (int k = 0; k < 8; ++k) acc[k] *= asc;
        m0 = nm0; m1 = nm1;
        const float e0 = (lane < n) ? __expf(v0 - nm0) : 0.f;
        const float e1 = (lane < n) ? __expf(v1 - nm1) : 0.f;
        float t0 = e0, t1 = e1;
        #pragma unroll
        for (int off = 32; off >= 1; off >>= 1) {
            t0 += __shfl_xor(t0, off, 64);
            t1 += __shfl_xor(t1, off, 64);
        }
        den0 += t0; den1 += t1;

        // fp16 gather: 4 edges per iteration, 16 lanes each (16B/lane)
        const int steps = (n + 3) >> 2;
        int j  = slot;
        int si = __shfl(s, j, 64);
        float4 raw = *(const float4*)&h[(size_t)si * 128 + p * 8];
        float av0 = __shfl(e0, j, 64);          // unconditional — full exec
        float av1 = __shfl(e1, j, 64);
        float av  = headhi ? av1 : av0;         // select on computed values: safe
        for (int i = 0; i < steps; ++i) {
            const float4 cur = raw;
            const float  ac  = av;
            if (i + 1 < steps) {
                j   = 4 * (i + 1) + slot;
                si  = __shfl(s, j, 64);
                raw = *(const float4*)&h[(size_t)si * 128 + p * 8];
                av0 = __shfl(e0, j, 64);
                av1 = __shfl(e1, j, 64);
                av  = headhi ? av1 : av0;
            }
            const __half2* hp = (const __half2*)&cur;
            #pragma unroll
            for (int k = 0; k < 4; ++k) {
                const float2 f = __half22float2(hp[k]);
                acc[2 * k]     += ac * f.x;
                acc[2 * k + 1] += ac * f.y;
            }
        }
    }
    // combine 4 edge slots
    #pragma unroll
    for (int k = 0; k < 8; ++k) {
        acc[k] += __shfl_xor(acc[k], 16, 64);
        acc[k] += __shfl_xor(acc[k], 32, 64);
    }
    if (slot == 0) {   // lanes 0..15 write the 128-ch row
        const float den = headhi ? den1 : den0;
        float o[8];
        #pragma unroll
        for (int k = 0; k < 8; ++k) {
            o[k] = acc[k] / den + b[p * 8 + k];
            o[k] = o[k] > 0.f ? o[k] : expm1f(o[k]);
        }
        *(float4*)&h2[(size_t)d * 128 + p * 8]     = make_float4(o[0], o[1], o[2], o[3]);
        *(float4*)&h2[(size_t)d * 128 + p * 8 + 4] = make_float4(o[4], o[5], o[6], o[7]);
    }
}

// ---------- layer 2 fused: chunked softmax + fp16 gather (8 edges/iter) ----------
// one 32-lane group per node. q: p2 = q&3 -> channels 8*p2..+7; slot2 = q>>2
__global__ __launch_bounds__(256) void fused_agg2_kernel(
    const int* __restrict__ csr_src, const int* __restrict__ offsets,
    const float* __restrict__ s_src, const float* __restrict__ s_dst,
    const __half* __restrict__ g, const float* __restrict__ b,
    float* __restrict__ out)
{
    const int grp      = threadIdx.x >> 5;
    const int q        = threadIdx.x & 31;
    const int halfbase = threadIdx.x & 32;
    const int p2       = q & 3;
    const int slot2    = q >> 2;
    const int d = blockIdx.x * 8 + grp;
    if (d >= N_NODES) return;
    const int beg = offsets[d], end = offsets[d + 1];
    const float sd = s_dst[d];
    float m = -1e30f, den = 0.f;
    float acc[8];
    #pragma unroll
    for (int k = 0; k < 8; ++k) acc[k] = 0.f;

    for (int pos = beg; pos < end; pos += 32) {
        const int n = min(32, end - pos);
        int s = 0;
        float v = -1e30f;
        if (q < n) {
            s = csr_src[pos + q];
            v = s_src[s] + sd;  v = v > 0.f ? v : 0.2f * v;
        }
        float cm = v;
        #pragma unroll
        for (int off = 16; off >= 1; off >>= 1)
            cm = fmaxf(cm, __shfl_xor(cm, off, 32));
        const float nm = fmaxf(m, cm);
        const float sc = __expf(m - nm);
        den *= sc;
        #pragma unroll
        for (int k = 0; k < 8; ++k) acc[k] *= sc;
        m = nm;
        const float e = (q < n) ? __expf(v - nm) : 0.f;
        float t = e;
        #pragma unroll
        for (int off = 16; off >= 1; off >>= 1)
            t += __shfl_xor(t, off, 32);
        den += t;

        // fp16 gather: 8 edges per iteration, 4 lanes each (16B/lane)
        const int steps = (n + 7) >> 3;
        int j  = slot2;
        int si = __shfl(s, halfbase + j, 64);
        float4 raw = *(const float4*)&g[(size_t)si * 32 + p2 * 8];
        float av = __shfl(e, halfbase + j, 64);
        for (int i = 0; i < steps; ++i) {
            const float4 cur = raw;
            const float  ac  = av;
            if (i + 1 < steps) {
                j  = 8 * (i + 1) + slot2;
                si = __shfl(s, halfbase + j, 64);
                raw = *(const float4*)&g[(size_t)si * 32 + p2 * 8];
                av  = __shfl(e, halfbase + j, 64);
            }
            const __half2* gp = (const __half2*)&cur;
            #pragma unroll
            for (int k = 0; k < 4; ++k) {
                const float2 f = __half22float2(gp[k]);
                acc[2 * k]     += ac * f.x;
                acc[2 * k + 1] += ac * f.y;
            }
        }
    }
    // combine 8 edge slots (within the 32-lane group)
    #pragma unroll
    for (int k = 0; k < 8; ++k) {
        acc[k] += __shfl_xor(acc[k], 4, 32);
        acc[k] += __shfl_xor(acc[k], 8, 32);
        acc[k] += __shfl_xor(acc[k], 16, 32);
    }
    if (slot2 == 0) {   // q < 4 write the 32-ch row
        float o[8];
        #pragma unroll
        for (int k = 0; k < 8; ++k)
            o[k] = acc[k] / den + b[p2 * 8 + k];
        *(float4*)&out[(size_t)d * 32 + p2 * 8]     = make_float4(o[0], o[1], o[2], o[3]);
        *(float4*)&out[(size_t)d * 32 + p2 * 8 + 4] = make_float4(o[4], o[5], o[6], o[7]);
    }
}

extern "C" void kernel_launch(void* const* d_in, const int* in_sizes, int n_in,
                              void* d_out, int out_size, void* d_ws, size_t ws_size,
                              hipStream_t stream)
{
    const float* x   = (const float*)d_in[0];
    const int*   ei  = (const int*)d_in[1];     // [2, E] int32: row0 = src, row1 = dst
    const float* W1  = (const float*)d_in[2];
    const float* a1s = (const float*)d_in[3];
    const float* a1d = (const float*)d_in[4];
    const float* b1  = (const float*)d_in[5];
    const float* W2  = (const float*)d_in[6];
    const float* a2s = (const float*)d_in[7];
    const float* a2d = (const float*)d_in[8];
    const float* b2  = (const float*)d_in[9];
    float* out = (float*)d_out;

    const int* esrc = ei;
    const int* edst = ei + N_EDGES;

    // -------- workspace layout (float-granular reservations) --------
    float* ws = (float*)d_ws;
    __half* h1 = (__half*)ws;                        // N*128 halfs (reserve N*128 floats)
    float* h2  = ws  + (size_t)N_NODES * 128;        // N*128 floats
    float* s1s = h2  + (size_t)N_NODES * 128;        // 2N
    float* s1d = s1s + 2 * N_NODES;                  // 2N
    float* s2s = s1d + 2 * N_NODES;                  // N
    float* s2d = s2s + N_NODES;                      // N
    int* deg     = (int*)(s2d + N_NODES);            // N
    int* offsets = deg + N_NODES;                    // N+1
    int* cursor  = offsets + N_NODES + 1;            // N
    int* csr_src = cursor + N_NODES;                 // E_TOT
    int* locscan = csr_src + E_TOT;                  // N
    int* partial = locscan + N_NODES;                // 64
    __half* g2 = (__half*)ws;                        // N*32 halfs (h1 dead after fused_agg1)

    // -------- CSR build --------
    hipMemsetAsync(deg, 0, (size_t)N_NODES * 4, stream);
    hist_kernel<<<(E_TOT + 255) / 256, 256, 0, stream>>>(edst, deg);
    scanA_kernel<<<SCAN_NB, SCAN_BLK, 0, stream>>>(deg, locscan, partial);
    scanB_kernel<<<1, 64, 0, stream>>>(partial);
    scanC_kernel<<<(N_NODES + 255) / 256, 256, 0, stream>>>(locscan, partial, offsets, cursor);
    scatter_kernel<<<(E_TOT + 255) / 256, 256, 0, stream>>>(esrc, edst, cursor, csr_src);

    // -------- layer 1 --------
    gemm1_tiled<<<((N_NODES + 63) / 64) * 2, 128, 0, stream>>>(x, W1, a1s, a1d, h1, s1s, s1d);
    fused_agg1_kernel<<<(N_NODES + 3) / 4, 256, 0, stream>>>(
        csr_src, offsets, s1s, s1d, h1, b1, h2);

    // -------- layer 2 --------
    gemm2_tiled<<<(N_NODES + 127) / 128, 128, 0, stream>>>(h2, W2, a2s, a2d, g2, s2s, s2d);
    fused_agg2_kernel<<<(N_NODES + 7) / 8, 256, 0, stream>>>(
        csr_src, offsets, s2s, s2d, g2, b2, out);
}

// Round 10
// 235.139 us; speedup vs baseline: 3.2602x; 1.0626x over previous
//
#include <hip/hip_runtime.h>
#include <hip/hip_fp16.h>
#include <math.h>

#define N_NODES 50000
#define N_EDGES 800000
#define E_TOT   (N_EDGES + N_NODES)   // 850000 edges incl. self loops
#define SCAN_BLK 1024
#define SCAN_NB  ((N_NODES + SCAN_BLK - 1) / SCAN_BLK)   // 49

// ================= layer 1 GEMM: h1 = x @ W1  [N,128]x[128,128] ================
// 256 threads, 128x64 tile (one head), 32 acc/thread. LDS 52KB -> 3 blocks/CU.
__global__ __launch_bounds__(256) void gemm1_tiled(
    const float* __restrict__ x, const float* __restrict__ W,
    const float* __restrict__ a_src, const float* __restrict__ a_dst,
    __half* __restrict__ h, float* __restrict__ s_src, float* __restrict__ s_dst)
{
    __shared__ float xs[128][68];
    __shared__ float wt[64][68];
    const int tid  = threadIdx.x;
    const int colT = tid & 15;
    const int rowT = tid >> 4;                // 0..15
    const int half = blockIdx.x & 1;          // head
    const int r0   = (blockIdx.x >> 1) * 128;
    const int c0   = half * 64;

    float acc[4][8];
    #pragma unroll
    for (int j = 0; j < 4; ++j)
        #pragma unroll
        for (int i = 0; i < 8; ++i) acc[j][i] = 0.f;

    for (int kc = 0; kc < 2; ++kc) {
        const int kbase = kc * 64;
        // stage xs: 128 rows x 16 quads = 2048 slots / 256 thr = 8 iters
        #pragma unroll
        for (int it = 0; it < 8; ++it) {
            int q = it * 256 + tid;
            int row = q >> 4, k4 = q & 15;
            float4 v = make_float4(0.f, 0.f, 0.f, 0.f);
            if (r0 + row < N_NODES)
                v = *(const float4*)&x[(size_t)(r0 + row) * 128 + kbase + k4 * 4];
            *(float4*)&xs[row][k4 * 4] = v;
        }
        // stage wt[c][k] = W[kbase+k][c0+c]: 64 c x 16 quads = 1024 slots / 256 = 4 iters
        #pragma unroll
        for (int it = 0; it < 4; ++it) {
            int q = it * 256 + tid;
            int c = q & 63, k4 = q >> 6;
            float4 v;
            v.x = W[(kbase + k4 * 4 + 0) * 128 + c0 + c];
            v.y = W[(kbase + k4 * 4 + 1) * 128 + c0 + c];
            v.z = W[(kbase + k4 * 4 + 2) * 128 + c0 + c];
            v.w = W[(kbase + k4 * 4 + 3) * 128 + c0 + c];
            *(float4*)&wt[c][k4 * 4] = v;
        }
        __syncthreads();
        #pragma unroll 4
        for (int k4 = 0; k4 < 16; ++k4) {
            float4 wv[4], xv[8];
            #pragma unroll
            for (int j = 0; j < 4; ++j) wv[j] = *(const float4*)&wt[colT + 16 * j][k4 * 4];
            #pragma unroll
            for (int i = 0; i < 8; ++i) xv[i] = *(const float4*)&xs[rowT + 16 * i][k4 * 4];
            #pragma unroll
            for (int j = 0; j < 4; ++j)
                #pragma unroll
                for (int i = 0; i < 8; ++i)
                    acc[j][i] += wv[j].x * xv[i].x + wv[j].y * xv[i].y
                               + wv[j].z * xv[i].z + wv[j].w * xv[i].w;
        }
        __syncthreads();
    }

    #pragma unroll
    for (int i = 0; i < 8; ++i) {
        const int row = r0 + rowT + 16 * i;
        float vs = 0.f, vd = 0.f;
        #pragma unroll
        for (int j = 0; j < 4; ++j) {
            const int c = c0 + colT + 16 * j;
            const float a = acc[j][i];
            vs += a * a_src[c];
            vd += a * a_dst[c];
            if (row < N_NODES) h[(size_t)row * 128 + c] = __float2half(a);
        }
        #pragma unroll
        for (int off = 8; off >= 1; off >>= 1) {
            vs += __shfl_xor(vs, off, 64);
            vd += __shfl_xor(vd, off, 64);
        }
        if (colT == 0 && row < N_NODES) {
            s_src[row * 2 + half] = vs;
            s_dst[row * 2 + half] = vd;
        }
    }
}

// ================= layer 2 GEMM: g = h2 @ W2  [N,128]x[128,32] ================
// 256 threads, 128x32 tile, 16 acc/thread. LDS 43.5KB -> 3 blocks/CU.
__global__ __launch_bounds__(256) void gemm2_tiled(
    const float* __restrict__ h2, const float* __restrict__ W,
    const float* __restrict__ a_src, const float* __restrict__ a_dst,
    __half* __restrict__ g, float* __restrict__ s_src, float* __restrict__ s_dst)
{
    __shared__ float xs[128][68];
    __shared__ float wt[32][68];
    const int tid  = threadIdx.x;
    const int colT = tid & 7;                 // 0..7
    const int rowT = tid >> 3;                // 0..31
    const int r0   = blockIdx.x * 128;

    float acc[4][4];
    #pragma unroll
    for (int j = 0; j < 4; ++j)
        #pragma unroll
        for (int i = 0; i < 4; ++i) acc[j][i] = 0.f;

    for (int kc = 0; kc < 2; ++kc) {
        const int kbase = kc * 64;
        // stage xs: 2048 slots / 256 = 8 iters
        #pragma unroll
        for (int it = 0; it < 8; ++it) {
            int q = it * 256 + tid;
            int row = q >> 4, k4 = q & 15;
            float4 v = make_float4(0.f, 0.f, 0.f, 0.f);
            if (r0 + row < N_NODES)
                v = *(const float4*)&h2[(size_t)(r0 + row) * 128 + kbase + k4 * 4];
            *(float4*)&xs[row][k4 * 4] = v;
        }
        // stage wt: 32 c x 16 quads = 512 slots / 256 = 2 iters
        #pragma unroll
        for (int it = 0; it < 2; ++it) {
            int q = it * 256 + tid;
            int c = q & 31, k4 = q >> 5;
            float4 v;
            v.x = W[(kbase + k4 * 4 + 0) * 32 + c];
            v.y = W[(kbase + k4 * 4 + 1) * 32 + c];
            v.z = W[(kbase + k4 * 4 + 2) * 32 + c];
            v.w = W[(kbase + k4 * 4 + 3) * 32 + c];
            *(float4*)&wt[c][k4 * 4] = v;
        }
        __syncthreads();
        #pragma unroll 4
        for (int k4 = 0; k4 < 16; ++k4) {
            float4 wv[4], xv[4];
            #pragma unroll
            for (int j = 0; j < 4; ++j) wv[j] = *(const float4*)&wt[colT + 8 * j][k4 * 4];
            #pragma unroll
            for (int i = 0; i < 4; ++i) xv[i] = *(const float4*)&xs[rowT + 32 * i][k4 * 4];
            #pragma unroll
            for (int j = 0; j < 4; ++j)
                #pragma unroll
                for (int i = 0; i < 4; ++i)
                    acc[j][i] += wv[j].x * xv[i].x + wv[j].y * xv[i].y
                               + wv[j].z * xv[i].z + wv[j].w * xv[i].w;
        }
        __syncthreads();
    }

    #pragma unroll
    for (int i = 0; i < 4; ++i) {
        const int row = r0 + rowT + 32 * i;
        float vs = 0.f, vd = 0.f;
        #pragma unroll
        for (int j = 0; j < 4; ++j) {
            const int c = colT + 8 * j;
            const float a = acc[j][i];
            vs += a * a_src[c];
            vd += a * a_dst[c];
            if (row < N_NODES) g[(size_t)row * 32 + c] = __float2half(a);
        }
        #pragma unroll
        for (int off = 4; off >= 1; off >>= 1) {
            vs += __shfl_xor(vs, off, 64);
            vd += __shfl_xor(vd, off, 64);
        }
        if (colT == 0 && row < N_NODES) {
            s_src[row] = vs;
            s_dst[row] = vd;
        }
    }
}

// ---------- CSR build ----------
__global__ void hist_kernel(const int* __restrict__ edst, int* __restrict__ deg)
{
    int e = blockIdx.x * blockDim.x + threadIdx.x;
    if (e >= E_TOT) return;
    int d = (e < N_EDGES) ? edst[e] : (e - N_EDGES);
    atomicAdd(&deg[d], 1);
}

__global__ __launch_bounds__(1024) void scanA_kernel(
    const int* __restrict__ deg, int* __restrict__ locscan, int* __restrict__ partial)
{
    __shared__ int buf[SCAN_BLK];
    const int t = threadIdx.x;
    const int i = blockIdx.x * SCAN_BLK + t;
    int v = (i < N_NODES) ? deg[i] : 0;
    buf[t] = v;
    __syncthreads();
    #pragma unroll
    for (int off = 1; off < SCAN_BLK; off <<= 1) {
        int xx = (t >= off) ? buf[t - off] : 0;
        __syncthreads();
        buf[t] += xx;
        __syncthreads();
    }
    if (i < N_NODES) locscan[i] = buf[t] - v;
    if (t == SCAN_BLK - 1) partial[blockIdx.x] = buf[t];
}

__global__ void scanB_kernel(int* __restrict__ partial)
{
    const int t = threadIdx.x;   // 0..63
    int orig = (t < SCAN_NB) ? partial[t] : 0;
    int v = orig;
    #pragma unroll
    for (int off = 1; off < 64; off <<= 1) {
        int xx = __shfl_up(v, off, 64);
        if (t >= off) v += xx;
    }
    if (t < SCAN_NB) partial[t] = v - orig;
}

__global__ void scanC_kernel(const int* __restrict__ locscan, const int* __restrict__ partial,
                             int* __restrict__ offsets, int* __restrict__ cursor)
{
    int i = blockIdx.x * 256 + threadIdx.x;
    if (i >= N_NODES) return;
    int o = locscan[i] + partial[i >> 10];
    offsets[i] = o;
    cursor[i]  = o;
    if (i == 0) offsets[N_NODES] = E_TOT;
}

__global__ void scatter_kernel(const int* __restrict__ esrc, const int* __restrict__ edst,
                               int* __restrict__ cursor, int* __restrict__ csr_src)
{
    int e = blockIdx.x * blockDim.x + threadIdx.x;
    if (e >= E_TOT) return;
    int s, d;
    if (e < N_EDGES) { s = esrc[e]; d = edst[e]; } else { s = d = e - N_EDGES; }
    int pos = atomicAdd(&cursor[d], 1);
    csr_src[pos] = s;
}

// ---------- layer 1 fused: chunked softmax + fp16 gather (4 edges/iter) ----------
// one wave per node. lane: p = lane&15 -> channels 8p..8p+7; slot = lane>>4 -> edge slot
// NOTE: all __shfl (ds_bpermute) calls are UNCONDITIONAL, full-exec — never inside
// a lane-divergent branch/ternary (convergent-op hazard, see round-4/round-7 bugs).
__global__ __launch_bounds__(256) void fused_agg1_kernel(
    const int* __restrict__ csr_src, const int* __restrict__ offsets,
    const float* __restrict__ s_src, const float* __restrict__ s_dst,
    const __half* __restrict__ h, const float* __restrict__ b,
    float* __restrict__ h2)
{
    const int wid  = threadIdx.x >> 6;
    const int lane = threadIdx.x & 63;
    const int p    = lane & 15;
    const int slot = lane >> 4;
    const bool headhi = p >= 8;           // channels 64..127
    const int d = blockIdx.x * 4 + wid;
    if (d >= N_NODES) return;
    const int beg = offsets[d], end = offsets[d + 1];
    const float sd0 = s_dst[d * 2], sd1 = s_dst[d * 2 + 1];
    float m0 = -1e30f, m1 = -1e30f;
    float den0 = 0.f, den1 = 0.f;
    float acc[8];
    #pragma unroll
    for (int k = 0; k < 8; ++k) acc[k] = 0.f;

    for (int pos = beg; pos < end; pos += 64) {
        const int n = min(64, end - pos);
        int s = 0;
        float v0 = -1e30f, v1 = -1e30f;
        if (lane < n) {
            s = csr_src[pos + lane];
            const float2 ss = *(const float2*)&s_src[s * 2];
            v0 = ss.x + sd0;  v0 = v0 > 0.f ? v0 : 0.2f * v0;
            v1 = ss.y + sd1;  v1 = v1 > 0.f ? v1 : 0.2f * v1;
        }
        float cm0 = v0, cm1 = v1;
        #pragma unroll
        for (int off = 32; off >= 1; off >>= 1) {
            cm0 = fmaxf(cm0, __shfl_xor(cm0, off, 64));
            cm1 = fmaxf(cm1, __shfl_xor(cm1, off, 64));
        }
        const float nm0 = fmaxf(m0, cm0), nm1 = fmaxf(m1, cm1);
        const float sc0 = __expf(m0 - nm0), sc1 = __expf(m1 - nm1);
        den0 *= sc0; den1 *= sc1;
        const float asc = headhi ? sc1 : sc0;
        #pragma unroll
        for (int k = 0; k < 8; ++k) acc[k] *= asc;
        m0 = nm0; m1 = nm1;
        const float e0 = (lane < n) ? __expf(v0 - nm0) : 0.f;
        const float e1 = (lane < n) ? __expf(v1 - nm1) : 0.f;
        float t0 = e0, t1 = e1;
        #pragma unroll
        for (int off = 32; off >= 1; off >>= 1) {
            t0 += __shfl_xor(t0, off, 64);
            t1 += __shfl_xor(t1, off, 64);
        }
        den0 += t0; den1 += t1;

        // fp16 gather: 4 edges per iteration, 16 lanes each (16B/lane)
        const int steps = (n + 3) >> 2;
        int j  = slot;
        int si = __shfl(s, j, 64);
        float4 raw = *(const float4*)&h[(size_t)si * 128 + p * 8];
        float av0 = __shfl(e0, j, 64);          // unconditional — full exec
        float av1 = __shfl(e1, j, 64);
        float av  = headhi ? av1 : av0;         // select on computed values: safe
        for (int i = 0; i < steps; ++i) {
            const float4 cur = raw;
            const float  ac  = av;
            if (i + 1 < steps) {
                j   = 4 * (i + 1) + slot;
                si  = __shfl(s, j, 64);
                raw = *(const float4*)&h[(size_t)si * 128 + p * 8];
                av0 = __shfl(e0, j, 64);
                av1 = __shfl(e1, j, 64);
                av  = headhi ? av1 : av0;
            }
            const __half2* hp = (const __half2*)&cur;
            #pragma unroll
            for (int k = 0; k < 4; ++k) {
                const float2 f = __half22float2(hp[k]);
                acc[2 * k]     += ac * f.x;
                acc[2 * k + 1] += ac * f.y;
            }
        }
    }
    // combine 4 edge slots
    #pragma unroll
    for (int k = 0; k < 8; ++k) {
        acc[k] += __shfl_xor(acc[k], 16, 64);
        acc[k] += __shfl_xor(acc[k], 32, 64);
    }
    if (slot == 0) {   // lanes 0..15 write the 128-ch row
        const float den = headhi ? den1 : den0;
        float o[8];
        #pragma unroll
        for (int k = 0; k < 8; ++k) {
            o[k] = acc[k] / den + b[p * 8 + k];
            o[k] = o[k] > 0.f ? o[k] : expm1f(o[k]);
        }
        *(float4*)&h2[(size_t)d * 128 + p * 8]     = make_float4(o[0], o[1], o[2], o[3]);
        *(float4*)&h2[(size_t)d * 128 + p * 8 + 4] = make_float4(o[4], o[5], o[6], o[7]);
    }
}

// ---------- layer 2 fused: chunked softmax + fp16 gather (8 edges/iter) ----------
// one 32-lane group per node. q: p2 = q&3 -> channels 8*p2..+7; slot2 = q>>2
__global__ __launch_bounds__(256) void fused_agg2_kernel(
    const int* __restrict__ csr_src, const int* __restrict__ offsets,
    const float* __restrict__ s_src, const float* __restrict__ s_dst,
    const __half* __restrict__ g, const float* __restrict__ b,
    float* __restrict__ out)
{
    const int grp      = threadIdx.x >> 5;
    const int q        = threadIdx.x & 31;
    const int halfbase = threadIdx.x & 32;
    const int p2       = q & 3;
    const int slot2    = q >> 2;
    const int d = blockIdx.x * 8 + grp;
    if (d >= N_NODES) return;
    const int beg = offsets[d], end = offsets[d + 1];
    const float sd = s_dst[d];
    float m = -1e30f, den = 0.f;
    float acc[8];
    #pragma unroll
    for (int k = 0; k < 8; ++k) acc[k] = 0.f;

    for (int pos = beg; pos < end; pos += 32) {
        const int n = min(32, end - pos);
        int s = 0;
        float v = -1e30f;
        if (q < n) {
            s = csr_src[pos + q];
            v = s_src[s] + sd;  v = v > 0.f ? v : 0.2f * v;
        }
        float cm = v;
        #pragma unroll
        for (int off = 16; off >= 1; off >>= 1)
            cm = fmaxf(cm, __shfl_xor(cm, off, 32));
        const float nm = fmaxf(m, cm);
        const float sc = __expf(m - nm);
        den *= sc;
        #pragma unroll
        for (int k = 0; k < 8; ++k) acc[k] *= sc;
        m = nm;
        const float e = (q < n) ? __expf(v - nm) : 0.f;
        float t = e;
        #pragma unroll
        for (int off = 16; off >= 1; off >>= 1)
            t += __shfl_xor(t, off, 32);
        den += t;

        // fp16 gather: 8 edges per iteration, 4 lanes each (16B/lane)
        const int steps = (n + 7) >> 3;
        int j  = slot2;
        int si = __shfl(s, halfbase + j, 64);
        float4 raw = *(const float4*)&g[(size_t)si * 32 + p2 * 8];
        float av = __shfl(e, halfbase + j, 64);
        for (int i = 0; i < steps; ++i) {
            const float4 cur = raw;
            const float  ac  = av;
            if (i + 1 < steps) {
                j  = 8 * (i + 1) + slot2;
                si = __shfl(s, halfbase + j, 64);
                raw = *(const float4*)&g[(size_t)si * 32 + p2 * 8];
                av  = __shfl(e, halfbase + j, 64);
            }
            const __half2* gp = (const __half2*)&cur;
            #pragma unroll
            for (int k = 0; k < 4; ++k) {
                const float2 f = __half22float2(gp[k]);
                acc[2 * k]     += ac * f.x;
                acc[2 * k + 1] += ac * f.y;
            }
        }
    }
    // combine 8 edge slots (within the 32-lane group)
    #pragma unroll
    for (int k = 0; k < 8; ++k) {
        acc[k] += __shfl_xor(acc[k], 4, 32);
        acc[k] += __shfl_xor(acc[k], 8, 32);
        acc[k] += __shfl_xor(acc[k], 16, 32);
    }
    if (slot2 == 0) {   // q < 4 write the 32-ch row
        float o[8];
        #pragma unroll
        for (int k = 0; k < 8; ++k)
            o[k] = acc[k] / den + b[p2 * 8 + k];
        *(float4*)&out[(size_t)d * 32 + p2 * 8]     = make_float4(o[0], o[1], o[2], o[3]);
        *(float4*)&out[(size_t)d * 32 + p2 * 8 + 4] = make_float4(o[4], o[5], o[6], o[7]);
    }
}

extern "C" void kernel_launch(void* const* d_in, const int* in_sizes, int n_in,
                              void* d_out, int out_size, void* d_ws, size_t ws_size,
                              hipStream_t stream)
{
    const float* x   = (const float*)d_in[0];
    const int*   ei  = (const int*)d_in[1];     // [2, E] int32: row0 = src, row1 = dst
    const float* W1  = (const float*)d_in[2];
    const float* a1s = (const float*)d_in[3];
    const float* a1d = (const float*)d_in[4];
    const float* b1  = (const float*)d_in[5];
    const float* W2  = (const float*)d_in[6];
    const float* a2s = (const float*)d_in[7];
    const float* a2d = (const float*)d_in[8];
    const float* b2  = (const float*)d_in[9];
    float* out = (float*)d_out;

    const int* esrc = ei;
    const int* edst = ei + N_EDGES;

    // -------- workspace layout (float-granular reservations) --------
    float* ws = (float*)d_ws;
    __half* h1 = (__half*)ws;                        // N*128 halfs (reserve N*128 floats)
    float* h2  = ws  + (size_t)N_NODES * 128;        // N*128 floats
    float* s1s = h2  + (size_t)N_NODES * 128;        // 2N
    float* s1d = s1s + 2 * N_NODES;                  // 2N
    float* s2s = s1d + 2 * N_NODES;                  // N
    float* s2d = s2s + N_NODES;                      // N
    int* deg     = (int*)(s2d + N_NODES);            // N
    int* offsets = deg + N_NODES;                    // N+1
    int* cursor  = offsets + N_NODES + 1;            // N
    int* csr_src = cursor + N_NODES;                 // E_TOT
    int* locscan = csr_src + E_TOT;                  // N
    int* partial = locscan + N_NODES;                // 64
    __half* g2 = (__half*)ws;                        // N*32 halfs (h1 dead after fused_agg1)

    // -------- CSR build --------
    hipMemsetAsync(deg, 0, (size_t)N_NODES * 4, stream);
    hist_kernel<<<(E_TOT + 255) / 256, 256, 0, stream>>>(edst, deg);
    scanA_kernel<<<SCAN_NB, SCAN_BLK, 0, stream>>>(deg, locscan, partial);
    scanB_kernel<<<1, 64, 0, stream>>>(partial);
    scanC_kernel<<<(N_NODES + 255) / 256, 256, 0, stream>>>(locscan, partial, offsets, cursor);
    scatter_kernel<<<(E_TOT + 255) / 256, 256, 0, stream>>>(esrc, edst, cursor, csr_src);

    // -------- layer 1 --------
    gemm1_tiled<<<((N_NODES + 127) / 128) * 2, 256, 0, stream>>>(x, W1, a1s, a1d, h1, s1s, s1d);
    fused_agg1_kernel<<<(N_NODES + 3) / 4, 256, 0, stream>>>(
        csr_src, offsets, s1s, s1d, h1, b1, h2);

    // -------- layer 2 --------
    gemm2_tiled<<<(N_NODES + 127) / 128, 256, 0, stream>>>(h2, W2, a2s, a2d, g2, s2s, s2d);
    fused_agg2_kernel<<<(N_NODES + 7) / 8, 256, 0, stream>>>(
        csr_src, offsets, s2s, s2d, g2, b2, out);
}